// Round 1
// baseline (344.094 us; speedup 1.0000x reference)
//
#include <hip/hip_runtime.h>

// MHSA fused pipeline, MI355X gfx950.
// B=2, N=2048, C=1024, H=16, dim=64.
// Layout fact: reshape(B,dim,H,N) is flat reinterpret -> per (b,h), Q/K/V are
// [d][n] with d-stride H*N=32768, n contiguous.
//
// Pipeline:
//  1) prep_w: Wp[o][c'] = bf16(W[o][d*16+h]), c' = h*64+d  (channel permute)
//  2) attn:   flash-style per (b,h,n-tile=64): QK^T via mfma 16x16x32 bf16,
//             online softmax fp32, PV via mfma; writes xt[b][n][c'] bf16
//  3) merge:  out[b][o][n] = sum_c' Wp[o][c'] * xt[b][n][c'] + bias[o]

#define H 16
#define DIM 64
#define NSEQ 2048
#define CCH 1024
#define BATCH 2

typedef __attribute__((ext_vector_type(8))) short bf16x8;
typedef __attribute__((ext_vector_type(4))) float f32x4;

__device__ __forceinline__ unsigned short f2bf(float x) {
  unsigned int u = __builtin_bit_cast(unsigned int, x);
  u += 0x7FFFu + ((u >> 16) & 1u);  // round-to-nearest-even
  return (unsigned short)(u >> 16);
}

__global__ __launch_bounds__(256) void prep_w(const float* __restrict__ W,
                                              unsigned short* __restrict__ Wp) {
  int idx = blockIdx.x * 256 + threadIdx.x;  // 1M elements
  int o = idx >> 10, cp = idx & 1023;
  int hh = cp >> 6, d = cp & 63;
  Wp[idx] = f2bf(W[o * CCH + d * H + hh]);
}

__global__ __launch_bounds__(256) void attn_kernel(const float* __restrict__ q,
                                                   const float* __restrict__ k,
                                                   const float* __restrict__ v,
                                                   unsigned short* __restrict__ xt) {
  // LDS tiles, padded to 72 (row = 144 B = 9*16 B -> b128-aligned rows)
  __shared__ __align__(16) unsigned short Qs[64][72];  // [n][d]
  __shared__ __align__(16) unsigned short Ks[64][72];  // [m][d]
  __shared__ __align__(16) unsigned short Vs[64][72];  // [d][m]
  __shared__ __align__(16) unsigned short Ps[4][16][72];  // per-wave P [n][m]

  const int tid = threadIdx.x;
  const int w = tid >> 6, lane = tid & 63;
  const int quad = lane >> 4, l16 = lane & 15;
  const int n0 = blockIdx.x * 64;
  const int hh = blockIdx.y;
  const int b = blockIdx.z;
  const int DSTR = H * NSEQ;  // 32768

  const size_t bofs = (size_t)b * (CCH * NSEQ) + (size_t)hh * NSEQ;
  const float* Qb = q + bofs;
  const float* Kb = k + bofs;
  const float* Vb = v + bofs;

  // stage Q transposed: Qs[n][d] = Q[d][n0+n]
#pragma unroll
  for (int r = 0; r < 4; ++r) {
    int i4 = r * 256 + tid;        // 1024 float4 loads
    int d = i4 >> 4;               // 16 float4 per d-row
    int nn = (i4 & 15) << 2;
    float4 val = *(const float4*)(Qb + (size_t)d * DSTR + n0 + nn);
    Qs[nn + 0][d] = f2bf(val.x);
    Qs[nn + 1][d] = f2bf(val.y);
    Qs[nn + 2][d] = f2bf(val.z);
    Qs[nn + 3][d] = f2bf(val.w);
  }
  __syncthreads();

  // Q A-fragments are m-loop invariant: A[row=n(l16)][k=d(quad*8+j)]
  bf16x8 aQ0 = *(const bf16x8*)&Qs[w * 16 + l16][quad * 8];
  bf16x8 aQ1 = *(const bf16x8*)&Qs[w * 16 + l16][32 + quad * 8];

  f32x4 O[4];
  float mrun[4], lrun[4];
#pragma unroll
  for (int r = 0; r < 4; ++r) {
    O[r] = (f32x4){0.f, 0.f, 0.f, 0.f};
    mrun[r] = -INFINITY;
    lrun[r] = 0.f;
  }
  const float scale = 0.022097086912079608f;  // 1/sqrt(2048)

  for (int m0 = 0; m0 < NSEQ; m0 += 64) {
    __syncthreads();  // prev iter's K/V reads done
#pragma unroll
    for (int r = 0; r < 4; ++r) {
      int i4 = r * 256 + tid;
      int d = i4 >> 4;
      int mm = (i4 & 15) << 2;
      float4 kv = *(const float4*)(Kb + (size_t)d * DSTR + m0 + mm);
      Ks[mm + 0][d] = f2bf(kv.x);
      Ks[mm + 1][d] = f2bf(kv.y);
      Ks[mm + 2][d] = f2bf(kv.z);
      Ks[mm + 3][d] = f2bf(kv.w);
      float4 vv = *(const float4*)(Vb + (size_t)d * DSTR + m0 + mm);
      Vs[d][mm + 0] = f2bf(vv.x);
      Vs[d][mm + 1] = f2bf(vv.y);
      Vs[d][mm + 2] = f2bf(vv.z);
      Vs[d][mm + 3] = f2bf(vv.w);
    }
    __syncthreads();

    // S[n(16 rows of this wave)][m(64)] = Q^T K, K-dim = dim = 64 (2 mfma steps)
    f32x4 S[4];
#pragma unroll
    for (int ms = 0; ms < 4; ++ms) {
      S[ms] = (f32x4){0.f, 0.f, 0.f, 0.f};
      bf16x8 bK0 = *(const bf16x8*)&Ks[ms * 16 + l16][quad * 8];
      S[ms] = __builtin_amdgcn_mfma_f32_16x16x32_bf16(aQ0, bK0, S[ms], 0, 0, 0);
      bf16x8 bK1 = *(const bf16x8*)&Ks[ms * 16 + l16][32 + quad * 8];
      S[ms] = __builtin_amdgcn_mfma_f32_16x16x32_bf16(aQ1, bK1, S[ms], 0, 0, 0);
    }

    // online softmax; D layout: row = quad*4+r, col = ms*16+l16
    float P[4][4];  // [ms][r]
    float rmax[4], rsum[4], alpha[4];
#pragma unroll
    for (int r = 0; r < 4; ++r) {
      float a0 = S[0][r] * scale, a1 = S[1][r] * scale;
      float a2 = S[2][r] * scale, a3 = S[3][r] * scale;
      P[0][r] = a0; P[1][r] = a1; P[2][r] = a2; P[3][r] = a3;
      rmax[r] = fmaxf(fmaxf(a0, a1), fmaxf(a2, a3));
    }
#pragma unroll
    for (int off = 1; off < 16; off <<= 1)
#pragma unroll
      for (int r = 0; r < 4; ++r)
        rmax[r] = fmaxf(rmax[r], __shfl_xor(rmax[r], off, 64));
#pragma unroll
    for (int r = 0; r < 4; ++r) {
      float mn = fmaxf(mrun[r], rmax[r]);
      alpha[r] = __expf(mrun[r] - mn);
      mrun[r] = mn;
      float s = 0.f;
#pragma unroll
      for (int ms = 0; ms < 4; ++ms) {
        float e = __expf(P[ms][r] - mn);
        P[ms][r] = e;
        s += e;
      }
      rsum[r] = s;
    }
#pragma unroll
    for (int off = 1; off < 16; off <<= 1)
#pragma unroll
      for (int r = 0; r < 4; ++r)
        rsum[r] += __shfl_xor(rsum[r], off, 64);
#pragma unroll
    for (int r = 0; r < 4; ++r) {
      lrun[r] = lrun[r] * alpha[r] + rsum[r];
#pragma unroll
      for (int d2 = 0; d2 < 4; ++d2) O[d2][r] *= alpha[r];
      // P -> LDS (C-layout to A-layout round trip)
#pragma unroll
      for (int ms = 0; ms < 4; ++ms)
        Ps[w][quad * 4 + r][ms * 16 + l16] = f2bf(P[ms][r]);
    }

    // PV: A = P[n][m(k)], B = Vt[m(k)][d]; same-wave DS ops execute in order
    bf16x8 aP0 = *(const bf16x8*)&Ps[w][l16][quad * 8];
    bf16x8 aP1 = *(const bf16x8*)&Ps[w][l16][32 + quad * 8];
#pragma unroll
    for (int d2 = 0; d2 < 4; ++d2) {
      bf16x8 bV0 = *(const bf16x8*)&Vs[d2 * 16 + l16][quad * 8];
      O[d2] = __builtin_amdgcn_mfma_f32_16x16x32_bf16(aP0, bV0, O[d2], 0, 0, 0);
      bf16x8 bV1 = *(const bf16x8*)&Vs[d2 * 16 + l16][32 + quad * 8];
      O[d2] = __builtin_amdgcn_mfma_f32_16x16x32_bf16(aP1, bV1, O[d2], 0, 0, 0);
    }
  }

  // epilogue: xt[b][n][c'=h*64+d] = O/l  (coalesced bf16 stores)
  const size_t xtbase = (size_t)b * ((size_t)NSEQ * CCH);
#pragma unroll
  for (int r = 0; r < 4; ++r) {
    float inv = 1.0f / lrun[r];
    int n = n0 + w * 16 + quad * 4 + r;
#pragma unroll
    for (int d2 = 0; d2 < 4; ++d2) {
      int cp = hh * 64 + d2 * 16 + l16;
      xt[xtbase + (size_t)n * CCH + cp] = f2bf(O[d2][r] * inv);
    }
  }
}

__global__ __launch_bounds__(256) void merge_kernel(const unsigned short* __restrict__ Wp,
                                                    const unsigned short* __restrict__ xt,
                                                    const float* __restrict__ bias,
                                                    float* __restrict__ out) {
  const int tid = threadIdx.x;
  const int w = tid >> 6, lane = tid & 63;
  const int quad = lane >> 4, l16 = lane & 15;
  const int n0 = blockIdx.x * 64;
  const int o0 = blockIdx.y * 64 + w * 16;
  const int b = blockIdx.z;
  const size_t xb = (size_t)b * ((size_t)NSEQ * CCH);

  f32x4 acc[4];
#pragma unroll
  for (int ns = 0; ns < 4; ++ns) acc[ns] = (f32x4){0.f, 0.f, 0.f, 0.f};

  for (int c0 = 0; c0 < CCH; c0 += 32) {
    bf16x8 aW = *(const bf16x8*)&Wp[(size_t)(o0 + l16) * CCH + c0 + quad * 8];
#pragma unroll
    for (int ns = 0; ns < 4; ++ns) {
      bf16x8 bX = *(const bf16x8*)&xt[xb + (size_t)(n0 + ns * 16 + l16) * CCH + c0 + quad * 8];
      acc[ns] = __builtin_amdgcn_mfma_f32_16x16x32_bf16(aW, bX, acc[ns], 0, 0, 0);
    }
  }
#pragma unroll
  for (int r = 0; r < 4; ++r) {
    int o = o0 + quad * 4 + r;
    float bi = bias[o];
#pragma unroll
    for (int ns = 0; ns < 4; ++ns) {
      out[(size_t)b * ((size_t)CCH * NSEQ) + (size_t)o * NSEQ + n0 + ns * 16 + l16] =
          acc[ns][r] + bi;
    }
  }
}

extern "C" void kernel_launch(void* const* d_in, const int* in_sizes, int n_in,
                              void* d_out, int out_size, void* d_ws, size_t ws_size,
                              hipStream_t stream) {
  const float* q = (const float*)d_in[0];
  const float* k = (const float*)d_in[1];
  const float* v = (const float*)d_in[2];
  const float* W = (const float*)d_in[3];
  const float* bias = (const float*)d_in[4];
  float* out = (float*)d_out;

  // ws layout: Wp bf16 [1024*1024] (2 MB) | xt bf16 [2*2048*1024] (8 MB)
  unsigned short* Wp = (unsigned short*)d_ws;
  unsigned short* xt = Wp + (size_t)CCH * CCH;

  hipLaunchKernelGGL(prep_w, dim3(CCH * CCH / 256), dim3(256), 0, stream, W, Wp);
  hipLaunchKernelGGL(attn_kernel, dim3(NSEQ / 64, H, BATCH), dim3(256), 0, stream,
                     q, k, v, xt);
  hipLaunchKernelGGL(merge_kernel, dim3(NSEQ / 64, CCH / 64, BATCH), dim3(256), 0, stream,
                     Wp, xt, bias, out);
}

// Round 2
// 198.975 us; speedup vs baseline: 1.7293x; 1.7293x over previous
//
#include <hip/hip_runtime.h>

// MHSA fused pipeline v2, MI355X gfx950.
// B=2, N=2048, C=1024, H=16, dim=64.
// Q/K/V per (b,h) are [d][n], d-stride H*N=32768, n contiguous.
//
// v2 changes vs v1 (which was latency/VALU-bound: MfmaUtil 6.5%):
//  - bf16 prep pass: Qt/Kt = [b][h][n][d] bf16 (scale folded into Q), Vb = flat bf16
//  - attn stages K/V/Q via global_load_lds(16B) into XOR-swizzled LDS (no VALU, no
//    scalar ds_write, conflict-free ds_read_b128 fragments)
//  - no-max softmax (scores bounded ~|1.5|): no shuffles/rescale in the loop;
//    one shuffle-reduce of the row-sum at the end
//  - n-tile 128 (4 waves x 32 rows), K/V double-buffered, 1 barrier/iter
//  - merge GEMM m97-style: 128x128 tile, BK=64, global_load_lds + swizzle

#define H 16
#define DIM 64
#define NSEQ 2048
#define CCH 1024
#define BATCH 2
#define DSTR (H * NSEQ)  // 32768

typedef __attribute__((ext_vector_type(8))) short bf16x8;
typedef __attribute__((ext_vector_type(4))) float f32x4;

__device__ __forceinline__ unsigned short f2bf(float x) {
  unsigned int u = __builtin_bit_cast(unsigned int, x);
  u += 0x7FFFu + ((u >> 16) & 1u);  // RNE
  return (unsigned short)(u >> 16);
}

__device__ __forceinline__ void gld16(const void* g, void* l) {
  __builtin_amdgcn_global_load_lds(
      (const __attribute__((address_space(1))) unsigned int*)g,
      (__attribute__((address_space(3))) unsigned int*)l, 16, 0, 0);
}

// ---------------- prep: W permute+convert ----------------
__global__ __launch_bounds__(256) void prep_w(const float* __restrict__ W,
                                              unsigned short* __restrict__ Wp) {
  int idx = blockIdx.x * 256 + threadIdx.x;  // 1Mi elements
  int o = idx >> 10, cp = idx & 1023;
  int hh = cp >> 6, d = cp & 63;
  Wp[idx] = f2bf(W[o * CCH + d * H + hh]);
}

// ---------------- prep: V flat convert ----------------
__global__ __launch_bounds__(256) void conv_v(const float* __restrict__ v,
                                              unsigned short* __restrict__ Vb) {
  int idx = blockIdx.x * 256 + threadIdx.x;  // 1Mi float4
  float4 x = ((const float4*)v)[idx];
  ushort4 o;
  o.x = f2bf(x.x); o.y = f2bf(x.y); o.z = f2bf(x.z); o.w = f2bf(x.w);
  ((ushort4*)Vb)[idx] = o;
}

// ---------------- prep: Q/K transpose+convert to [b][h][n][d] ----------------
__global__ __launch_bounds__(256) void prep_tr(const float* __restrict__ q,
                                               const float* __restrict__ k,
                                               unsigned short* __restrict__ Qt,
                                               unsigned short* __restrict__ Kt) {
  __shared__ unsigned short T[64][72];
  const int tid = threadIdx.x;
  const int n0 = blockIdx.x * 64;
  const int hh = blockIdx.y;
  const int b = blockIdx.z >> 1, t = blockIdx.z & 1;
  const float* src = t ? k : q;
  unsigned short* dst = t ? Kt : Qt;
  const float scl = t ? 1.0f : 0.022097086912079608f;  // 1/sqrt(2048) folded into Q
  const size_t base = (size_t)b * (CCH * NSEQ) + (size_t)hh * NSEQ;
#pragma unroll
  for (int it = 0; it < 4; ++it) {
    int i4 = it * 256 + tid;
    int d = i4 >> 4;
    int nn = (i4 & 15) << 2;
    float4 val = *(const float4*)(src + base + (size_t)d * DSTR + n0 + nn);
    T[nn + 0][d] = f2bf(val.x * scl);
    T[nn + 1][d] = f2bf(val.y * scl);
    T[nn + 2][d] = f2bf(val.z * scl);
    T[nn + 3][d] = f2bf(val.w * scl);
  }
  __syncthreads();
  const size_t obase = ((size_t)(b * H + hh) * NSEQ + n0) * 64;
#pragma unroll
  for (int it = 0; it < 2; ++it) {
    int idx = it * 256 + tid;
    int row = idx >> 3, cb = idx & 7;
    *(bf16x8*)(dst + obase + (size_t)row * 64 + cb * 8) = *(const bf16x8*)&T[row][cb * 8];
  }
}

// ---------------- attention ----------------
__global__ __launch_bounds__(256) void attn2(const unsigned short* __restrict__ Qt,
                                             const unsigned short* __restrict__ Kt,
                                             const unsigned short* __restrict__ Vb,
                                             unsigned short* __restrict__ xt) {
  __shared__ unsigned short Qs[128 * 64];     // 16 KB, swizzled
  __shared__ unsigned short Ks[2][64 * 64];   // 2 x 8 KB, swizzled
  __shared__ unsigned short Vs[2][64 * 64];   // 2 x 8 KB, swizzled
  __shared__ unsigned short Ps[4][32][72];    // 18.4 KB, per-wave P

  const int tid = threadIdx.x;
  const int w = tid >> 6, lane = tid & 63;
  const int quad = lane >> 4, l16 = lane & 15;
  const int n0 = blockIdx.x * 128;
  const int hh = blockIdx.y, b = blockIdx.z;

  const unsigned short* Qbase = Qt + ((size_t)(b * H + hh) * NSEQ + n0) * 64;
  const unsigned short* Kbase = Kt + ((size_t)(b * H + hh) * NSEQ) * 64;
  const unsigned short* Vbase = Vb + (size_t)b * (CCH * NSEQ) + (size_t)hh * NSEQ;

  const int srow = w * 8 + (lane >> 3);  // staging row within a 32-row issue
  const int scb = lane & 7;

  // stage Q: 4 issues x 32 rows (swizzle: phys cb = logical cb ^ (row&7))
#pragma unroll
  for (int i = 0; i < 4; ++i) {
    int row = i * 32 + srow;
    int cbl = scb ^ (row & 7);
    gld16(Qbase + (size_t)row * 64 + cbl * 8, &Qs[(i * 32 + w * 8) * 64]);
  }
  // stage K/V tile 0 into buffer 0
#pragma unroll
  for (int i = 0; i < 2; ++i) {
    int row = i * 32 + srow;
    int cbl = scb ^ (row & 7);
    gld16(Kbase + (size_t)row * 64 + cbl * 8, &Ks[0][(i * 32 + w * 8) * 64]);
    gld16(Vbase + (size_t)row * DSTR + cbl * 8, &Vs[0][(i * 32 + w * 8) * 64]);
  }
  __syncthreads();

  // loop-invariant Q fragments: A[row=n][k=d]
  bf16x8 aQ[2][2];
#pragma unroll
  for (int nt = 0; nt < 2; ++nt)
#pragma unroll
    for (int kh = 0; kh < 2; ++kh) {
      int row = w * 32 + nt * 16 + l16;
      int phys = (kh * 4 + quad) ^ (l16 & 7);
      aQ[nt][kh] = *(const bf16x8*)&Qs[(size_t)row * 64 + phys * 8];
    }

  f32x4 O[2][4];
  float lsum[2][4];
#pragma unroll
  for (int nt = 0; nt < 2; ++nt) {
#pragma unroll
    for (int dt = 0; dt < 4; ++dt) O[nt][dt] = (f32x4){0.f, 0.f, 0.f, 0.f};
#pragma unroll
    for (int r = 0; r < 4; ++r) lsum[nt][r] = 0.f;
  }

  for (int it = 0; it < 32; ++it) {
    const int cur = it & 1;
    // prefetch next K/V tile into the other buffer (overlaps with compute below)
    if (it + 1 < 32) {
      const int nxt = cur ^ 1;
      const int m0n = (it + 1) * 64;
#pragma unroll
      for (int i = 0; i < 2; ++i) {
        int row = i * 32 + srow;
        int cbl = scb ^ (row & 7);
        gld16(Kbase + (size_t)(m0n + row) * 64 + cbl * 8, &Ks[nxt][(i * 32 + w * 8) * 64]);
        gld16(Vbase + (size_t)row * DSTR + m0n + cbl * 8, &Vs[nxt][(i * 32 + w * 8) * 64]);
      }
    }

    // S[n(32 rows)][m(64)] = Qt . Kt^T  (K-dim = 64 = 2 mfma k-slices)
    f32x4 S[2][4];
#pragma unroll
    for (int nt = 0; nt < 2; ++nt)
#pragma unroll
      for (int ms = 0; ms < 4; ++ms) S[nt][ms] = (f32x4){0.f, 0.f, 0.f, 0.f};
#pragma unroll
    for (int ms = 0; ms < 4; ++ms)
#pragma unroll
      for (int kh = 0; kh < 2; ++kh) {
        int row = ms * 16 + l16;
        int phys = (kh * 4 + quad) ^ (l16 & 7);
        bf16x8 bK = *(const bf16x8*)&Ks[cur][(size_t)row * 64 + phys * 8];
        S[0][ms] = __builtin_amdgcn_mfma_f32_16x16x32_bf16(aQ[0][kh], bK, S[0][ms], 0, 0, 0);
        S[1][ms] = __builtin_amdgcn_mfma_f32_16x16x32_bf16(aQ[1][kh], bK, S[1][ms], 0, 0, 0);
      }

    // no-max softmax: P = exp(S) (S pre-scaled via Q prep, |S| <~ 1.5)
    // C-layout: row = quad*4+r, col = ms*16+l16
#pragma unroll
    for (int nt = 0; nt < 2; ++nt)
#pragma unroll
      for (int ms = 0; ms < 4; ++ms)
#pragma unroll
        for (int r = 0; r < 4; ++r) {
          float e = __expf(S[nt][ms][r]);
          lsum[nt][r] += e;
          Ps[w][nt * 16 + quad * 4 + r][ms * 16 + l16] = f2bf(e);
        }

    // PV: A = P[n][m], B-frag = V[d=col][m=k] (V natural layout)
    bf16x8 aP[2][2];
#pragma unroll
    for (int nt = 0; nt < 2; ++nt)
#pragma unroll
      for (int kh = 0; kh < 2; ++kh)
        aP[nt][kh] = *(const bf16x8*)&Ps[w][nt * 16 + l16][kh * 32 + quad * 8];
#pragma unroll
    for (int dt = 0; dt < 4; ++dt)
#pragma unroll
      for (int kh = 0; kh < 2; ++kh) {
        int row = dt * 16 + l16;
        int phys = (kh * 4 + quad) ^ (l16 & 7);
        bf16x8 bV = *(const bf16x8*)&Vs[cur][(size_t)row * 64 + phys * 8];
        O[0][dt] = __builtin_amdgcn_mfma_f32_16x16x32_bf16(aP[0][kh], bV, O[0][dt], 0, 0, 0);
        O[1][dt] = __builtin_amdgcn_mfma_f32_16x16x32_bf16(aP[1][kh], bV, O[1][dt], 0, 0, 0);
      }

    __syncthreads();  // drains prefetch (vmcnt) + protects buffer reuse
  }

  // final row-sum reduce across the 16 col-lanes, then normalize + store
#pragma unroll
  for (int nt = 0; nt < 2; ++nt)
#pragma unroll
    for (int r = 0; r < 4; ++r) {
#pragma unroll
      for (int off = 1; off < 16; off <<= 1)
        lsum[nt][r] += __shfl_xor(lsum[nt][r], off, 64);
    }

  const size_t xb = (size_t)b * ((size_t)NSEQ * CCH);
#pragma unroll
  for (int nt = 0; nt < 2; ++nt)
#pragma unroll
    for (int r = 0; r < 4; ++r) {
      float inv = 1.0f / lsum[nt][r];
      int n = n0 + w * 32 + nt * 16 + quad * 4 + r;
#pragma unroll
      for (int dt = 0; dt < 4; ++dt) {
        int cp = hh * 64 + dt * 16 + l16;
        xt[xb + (size_t)n * CCH + cp] = f2bf(O[nt][dt][r] * inv);
      }
    }
}

// ---------------- merge GEMM (m97-style) ----------------
__global__ __launch_bounds__(256) void merge2(const unsigned short* __restrict__ Wp,
                                              const unsigned short* __restrict__ xt,
                                              const float* __restrict__ bias,
                                              float* __restrict__ out) {
  __shared__ unsigned short At[128 * 64];  // 16 KB, swizzled
  __shared__ unsigned short Bt[128 * 64];  // 16 KB, swizzled
  const int tid = threadIdx.x;
  const int w = tid >> 6, lane = tid & 63;
  const int quad = lane >> 4, l16 = lane & 15;
  const int wx = w & 1, wy = w >> 1;
  const int n0 = blockIdx.x * 128, o0 = blockIdx.y * 128, b = blockIdx.z;
  const int srow = w * 8 + (lane >> 3), scb = lane & 7;
  const unsigned short* Bbase = xt + (size_t)b * ((size_t)NSEQ * CCH);

  f32x4 acc[4][4];
#pragma unroll
  for (int ot = 0; ot < 4; ++ot)
#pragma unroll
    for (int nt = 0; nt < 4; ++nt) acc[ot][nt] = (f32x4){0.f, 0.f, 0.f, 0.f};

  for (int c0 = 0; c0 < CCH; c0 += 64) {
    __syncthreads();
#pragma unroll
    for (int i = 0; i < 4; ++i) {
      int row = i * 32 + srow;
      int cbl = scb ^ (row & 7);
      gld16(Wp + (size_t)(o0 + row) * CCH + c0 + cbl * 8, &At[(i * 32 + w * 8) * 64]);
      gld16(Bbase + (size_t)(n0 + row) * CCH + c0 + cbl * 8, &Bt[(i * 32 + w * 8) * 64]);
    }
    __syncthreads();
#pragma unroll
    for (int ks = 0; ks < 2; ++ks) {
      bf16x8 aW[4], bX[4];
      int phys = ((ks * 4 + quad) ^ (l16 & 7)) * 8;
#pragma unroll
      for (int t = 0; t < 4; ++t) {
        aW[t] = *(const bf16x8*)&At[(wy * 64 + t * 16 + l16) * 64 + phys];
        bX[t] = *(const bf16x8*)&Bt[(wx * 64 + t * 16 + l16) * 64 + phys];
      }
#pragma unroll
      for (int ot = 0; ot < 4; ++ot)
#pragma unroll
        for (int nt = 0; nt < 4; ++nt)
          acc[ot][nt] = __builtin_amdgcn_mfma_f32_16x16x32_bf16(aW[ot], bX[nt], acc[ot][nt], 0, 0, 0);
    }
  }

#pragma unroll
  for (int ot = 0; ot < 4; ++ot)
#pragma unroll
    for (int r = 0; r < 4; ++r) {
      int o = o0 + wy * 64 + ot * 16 + quad * 4 + r;
      float bi = bias[o];
#pragma unroll
      for (int nt = 0; nt < 4; ++nt)
        out[(size_t)b * ((size_t)CCH * NSEQ) + (size_t)o * NSEQ + n0 + wx * 64 + nt * 16 + l16] =
            acc[ot][nt][r] + bi;
    }
}

extern "C" void kernel_launch(void* const* d_in, const int* in_sizes, int n_in,
                              void* d_out, int out_size, void* d_ws, size_t ws_size,
                              hipStream_t stream) {
  const float* q = (const float*)d_in[0];
  const float* k = (const float*)d_in[1];
  const float* v = (const float*)d_in[2];
  const float* W = (const float*)d_in[3];
  const float* bias = (const float*)d_in[4];
  float* out = (float*)d_out;

  // ws layout (ushort units): Wp 1Mi | xt 4Mi | Qt 4Mi | Kt 4Mi | Vb 4Mi = 34 MiB
  unsigned short* Wp = (unsigned short*)d_ws;
  unsigned short* xt = Wp + (1u << 20);
  unsigned short* Qt = xt + (4u << 20);
  unsigned short* Kt = Qt + (4u << 20);
  unsigned short* Vb = Kt + (4u << 20);

  hipLaunchKernelGGL(prep_w, dim3(4096), dim3(256), 0, stream, W, Wp);
  hipLaunchKernelGGL(conv_v, dim3(4096), dim3(256), 0, stream, v, Vb);
  hipLaunchKernelGGL(prep_tr, dim3(NSEQ / 64, H, BATCH * 2), dim3(256), 0, stream,
                     q, k, Qt, Kt);
  hipLaunchKernelGGL(attn2, dim3(NSEQ / 128, H, BATCH), dim3(256), 0, stream,
                     Qt, Kt, Vb, xt);
  hipLaunchKernelGGL(merge2, dim3(NSEQ / 128, CCH / 128, BATCH), dim3(256), 0, stream,
                     Wp, xt, bias, out);
}

// Round 3
// 191.587 us; speedup vs baseline: 1.7960x; 1.0386x over previous
//
#include <hip/hip_runtime.h>

// MHSA fused pipeline v3, MI355X gfx950.
// B=2, N=2048, C=1024, H=16, dim=64.
// Q/K/V per (b,h) are [d][n], d-stride H*N=32768, n contiguous.
//
// v3 changes vs v2 (attn2: MfmaUtil 18%, VALUBusy 47%, occ 19.5%, 77us):
//  - QK computed TRANSPOSED (St = K*Q^T, operands swapped): C-layout then holds
//    4 consecutive m per lane -> P written as 8x ds_write_b64 (was 32x b16)
//  - P pack via v_cvt_pk_bf16_f32 (1 instr RNE pack; guarded fallback)
//  - log2(e) folded into Q scale -> exp2 directly (no per-element mul)
//  - Qs/Ps LDS union (Q only read pre-loop into regs): 66->50.4 KB, 3 blocks/CU

#define H 16
#define DIM 64
#define NSEQ 2048
#define CCH 1024
#define BATCH 2
#define DSTR (H * NSEQ)  // 32768
#define PSP 72           // Ps pitch (shorts): 144 B rows -> 2-way max on b64/b128

typedef __attribute__((ext_vector_type(8))) short bf16x8;
typedef __attribute__((ext_vector_type(4))) float f32x4;

__device__ __forceinline__ unsigned short f2bf(float x) {
  unsigned int u = __builtin_bit_cast(unsigned int, x);
  u += 0x7FFFu + ((u >> 16) & 1u);  // RNE
  return (unsigned short)(u >> 16);
}

// pack two f32 -> packed bf16 pair (lo = a, hi = b), RNE
__device__ __forceinline__ unsigned int pack2bf(float a, float b) {
#if __has_builtin(__builtin_amdgcn_cvt_pk_bf16_f32)
  typedef __attribute__((ext_vector_type(2))) __bf16 bf16x2_t;
  bf16x2_t r = __builtin_amdgcn_cvt_pk_bf16_f32(a, b);
  return __builtin_bit_cast(unsigned int, r);
#else
  unsigned int ua = __builtin_bit_cast(unsigned int, a);
  unsigned int ub = __builtin_bit_cast(unsigned int, b);
  ua += 0x7FFFu + ((ua >> 16) & 1u);
  ub += 0x7FFFu + ((ub >> 16) & 1u);
  return __builtin_amdgcn_perm(ub, ua, 0x07060302u);  // [ua.b2,ua.b3,ub.b2,ub.b3]
#endif
}

__device__ __forceinline__ float fast_exp2(float x) {
#if __has_builtin(__builtin_amdgcn_exp2f)
  return __builtin_amdgcn_exp2f(x);
#else
  return exp2f(x);
#endif
}

__device__ __forceinline__ void gld16(const void* g, void* l) {
  __builtin_amdgcn_global_load_lds(
      (const __attribute__((address_space(1))) unsigned int*)g,
      (__attribute__((address_space(3))) unsigned int*)l, 16, 0, 0);
}

// ---------------- prep: W permute+convert ----------------
__global__ __launch_bounds__(256) void prep_w(const float* __restrict__ W,
                                              unsigned short* __restrict__ Wp) {
  int idx = blockIdx.x * 256 + threadIdx.x;  // 1Mi elements
  int o = idx >> 10, cp = idx & 1023;
  int hh = cp >> 6, d = cp & 63;
  Wp[idx] = f2bf(W[o * CCH + d * H + hh]);
}

// ---------------- prep: V flat convert ----------------
__global__ __launch_bounds__(256) void conv_v(const float* __restrict__ v,
                                              unsigned short* __restrict__ Vb) {
  int idx = blockIdx.x * 256 + threadIdx.x;  // 1Mi float4
  float4 x = ((const float4*)v)[idx];
  ushort4 o;
  o.x = f2bf(x.x); o.y = f2bf(x.y); o.z = f2bf(x.z); o.w = f2bf(x.w);
  ((ushort4*)Vb)[idx] = o;
}

// ---------------- prep: Q/K transpose+convert to [b][h][n][d] ----------------
__global__ __launch_bounds__(256) void prep_tr(const float* __restrict__ q,
                                               const float* __restrict__ k,
                                               unsigned short* __restrict__ Qt,
                                               unsigned short* __restrict__ Kt) {
  __shared__ unsigned short T[64][72];
  const int tid = threadIdx.x;
  const int n0 = blockIdx.x * 64;
  const int hh = blockIdx.y;
  const int b = blockIdx.z >> 1, t = blockIdx.z & 1;
  const float* src = t ? k : q;
  unsigned short* dst = t ? Kt : Qt;
  // Q scale: 1/sqrt(2048) * log2(e)  (exp(x) == exp2(x*log2e))
  const float scl = t ? 1.0f : (0.022097086912079608f * 1.4426950408889634f);
  const size_t base = (size_t)b * (CCH * NSEQ) + (size_t)hh * NSEQ;
#pragma unroll
  for (int it = 0; it < 4; ++it) {
    int i4 = it * 256 + tid;
    int d = i4 >> 4;
    int nn = (i4 & 15) << 2;
    float4 val = *(const float4*)(src + base + (size_t)d * DSTR + n0 + nn);
    T[nn + 0][d] = f2bf(val.x * scl);
    T[nn + 1][d] = f2bf(val.y * scl);
    T[nn + 2][d] = f2bf(val.z * scl);
    T[nn + 3][d] = f2bf(val.w * scl);
  }
  __syncthreads();
  const size_t obase = ((size_t)(b * H + hh) * NSEQ + n0) * 64;
#pragma unroll
  for (int it = 0; it < 2; ++it) {
    int idx = it * 256 + tid;
    int row = idx >> 3, cb = idx & 7;
    *(bf16x8*)(dst + obase + (size_t)row * 64 + cb * 8) = *(const bf16x8*)&T[row][cb * 8];
  }
}

// ---------------- attention ----------------
__global__ __launch_bounds__(256) void attn3(const unsigned short* __restrict__ Qt,
                                             const unsigned short* __restrict__ Kt,
                                             const unsigned short* __restrict__ Vb,
                                             unsigned short* __restrict__ xt) {
  __shared__ __align__(16) unsigned short Ks[2][64 * 64];  // 2 x 8 KB, swizzled
  __shared__ __align__(16) unsigned short Vs[2][64 * 64];  // 2 x 8 KB, swizzled
  // union: Qs[128*64] (16 KB, swizzled) pre-loop / Ps[4][32][PSP] (18 KB) in-loop
  __shared__ __align__(16) unsigned short UQ[4 * 32 * PSP];
  unsigned short* Qs = UQ;
  unsigned short* Ps = UQ;

  const int tid = threadIdx.x;
  const int w = tid >> 6, lane = tid & 63;
  const int quad = lane >> 4, l16 = lane & 15;
  const int n0 = blockIdx.x * 128;
  const int hh = blockIdx.y, b = blockIdx.z;

  const unsigned short* Qbase = Qt + ((size_t)(b * H + hh) * NSEQ + n0) * 64;
  const unsigned short* Kbase = Kt + ((size_t)(b * H + hh) * NSEQ) * 64;
  const unsigned short* Vbase = Vb + (size_t)b * (CCH * NSEQ) + (size_t)hh * NSEQ;

  const int srow = w * 8 + (lane >> 3);
  const int scb = lane & 7;

  // stage Q (into union) + K/V tile 0; swizzle: phys cb = logical cb ^ (row&7)
#pragma unroll
  for (int i = 0; i < 4; ++i) {
    int row = i * 32 + srow;
    int cbl = scb ^ (row & 7);
    gld16(Qbase + (size_t)row * 64 + cbl * 8, &Qs[(i * 32 + w * 8) * 64]);
  }
#pragma unroll
  for (int i = 0; i < 2; ++i) {
    int row = i * 32 + srow;
    int cbl = scb ^ (row & 7);
    gld16(Kbase + (size_t)row * 64 + cbl * 8, &Ks[0][(i * 32 + w * 8) * 64]);
    gld16(Vbase + (size_t)row * DSTR + cbl * 8, &Vs[0][(i * 32 + w * 8) * 64]);
  }
  __syncthreads();

  // Q fragments (B-operand of St): B[col=n][k=d]; loop-invariant
  bf16x8 bQ[2][2];
#pragma unroll
  for (int nt = 0; nt < 2; ++nt)
#pragma unroll
    for (int kh = 0; kh < 2; ++kh) {
      int row = w * 32 + nt * 16 + l16;
      int phys = (kh * 4 + quad) ^ (l16 & 7);
      bQ[nt][kh] = *(const bf16x8*)&Qs[(size_t)row * 64 + phys * 8];
    }
  __syncthreads();  // after this, UQ is Ps

  f32x4 O[2][4];
  float lsum[2] = {0.f, 0.f};
#pragma unroll
  for (int nt = 0; nt < 2; ++nt)
#pragma unroll
    for (int dt = 0; dt < 4; ++dt) O[nt][dt] = (f32x4){0.f, 0.f, 0.f, 0.f};

  const int psw = w * 32 * PSP;  // per-wave Ps base (shorts)

  for (int it = 0; it < 32; ++it) {
    const int cur = it & 1;
    if (it + 1 < 32) {
      const int nxt = cur ^ 1;
      const int m0n = (it + 1) * 64;
#pragma unroll
      for (int i = 0; i < 2; ++i) {
        int row = i * 32 + srow;
        int cbl = scb ^ (row & 7);
        gld16(Kbase + (size_t)(m0n + row) * 64 + cbl * 8, &Ks[nxt][(i * 32 + w * 8) * 64]);
        gld16(Vbase + (size_t)row * DSTR + m0n + cbl * 8, &Vs[nxt][(i * 32 + w * 8) * 64]);
      }
    }

    // St[m][n] = K . Q^T (transposed scores): A=K[m][d], B=Q[n][d]
    f32x4 St[4][2];
#pragma unroll
    for (int mt = 0; mt < 4; ++mt)
#pragma unroll
      for (int nt = 0; nt < 2; ++nt) St[mt][nt] = (f32x4){0.f, 0.f, 0.f, 0.f};
#pragma unroll
    for (int mt = 0; mt < 4; ++mt)
#pragma unroll
      for (int kh = 0; kh < 2; ++kh) {
        int row = mt * 16 + l16;
        int phys = (kh * 4 + quad) ^ (l16 & 7);
        bf16x8 aK = *(const bf16x8*)&Ks[cur][(size_t)row * 64 + phys * 8];
        St[mt][0] = __builtin_amdgcn_mfma_f32_16x16x32_bf16(aK, bQ[0][kh], St[mt][0], 0, 0, 0);
        St[mt][1] = __builtin_amdgcn_mfma_f32_16x16x32_bf16(aK, bQ[1][kh], St[mt][1], 0, 0, 0);
      }

    // P = exp2(St) (log2e pre-folded); St C-layout: row m = mt*16+quad*4+r,
    // col n = nt*16+l16 -> 4 consecutive m per lane -> pack into one b64 write
#pragma unroll
    for (int nt = 0; nt < 2; ++nt) {
#pragma unroll
      for (int mt = 0; mt < 4; ++mt) {
        float e0 = fast_exp2(St[mt][nt][0]);
        float e1 = fast_exp2(St[mt][nt][1]);
        float e2 = fast_exp2(St[mt][nt][2]);
        float e3 = fast_exp2(St[mt][nt][3]);
        lsum[nt] += (e0 + e1) + (e2 + e3);
        uint2 pk;
        pk.x = pack2bf(e0, e1);
        pk.y = pack2bf(e2, e3);
        *(uint2*)&Ps[psw + (nt * 16 + l16) * PSP + mt * 16 + quad * 4] = pk;
      }
    }

    // PV: O[n][d] = P[n][m] . V[d][m]; A=P (from Ps), B=V (natural layout)
    bf16x8 aP[2][2];
#pragma unroll
    for (int nt = 0; nt < 2; ++nt)
#pragma unroll
      for (int kh = 0; kh < 2; ++kh)
        aP[nt][kh] = *(const bf16x8*)&Ps[psw + (nt * 16 + l16) * PSP + kh * 32 + quad * 8];
#pragma unroll
    for (int dt = 0; dt < 4; ++dt)
#pragma unroll
      for (int kh = 0; kh < 2; ++kh) {
        int row = dt * 16 + l16;
        int phys = (kh * 4 + quad) ^ (l16 & 7);
        bf16x8 bV = *(const bf16x8*)&Vs[cur][(size_t)row * 64 + phys * 8];
        O[0][dt] = __builtin_amdgcn_mfma_f32_16x16x32_bf16(aP[0][kh], bV, O[0][dt], 0, 0, 0);
        O[1][dt] = __builtin_amdgcn_mfma_f32_16x16x32_bf16(aP[1][kh], bV, O[1][dt], 0, 0, 0);
      }

    __syncthreads();  // drains prefetch + protects buffer reuse
  }

  // lsum: partial sums live across quads (lane bits 4,5) at fixed l16
#pragma unroll
  for (int nt = 0; nt < 2; ++nt) {
    lsum[nt] += __shfl_xor(lsum[nt], 16, 64);
    lsum[nt] += __shfl_xor(lsum[nt], 32, 64);
  }

  const size_t xb = (size_t)b * ((size_t)NSEQ * CCH);
#pragma unroll
  for (int nt = 0; nt < 2; ++nt)
#pragma unroll
    for (int r = 0; r < 4; ++r) {
      float inv = 1.0f / __shfl(lsum[nt], quad * 4 + r, 64);
      int n = n0 + w * 32 + nt * 16 + quad * 4 + r;
#pragma unroll
      for (int dt = 0; dt < 4; ++dt) {
        int cp = hh * 64 + dt * 16 + l16;
        xt[xb + (size_t)n * CCH + cp] = f2bf(O[nt][dt][r] * inv);
      }
    }
}

// ---------------- merge GEMM (m97-style) ----------------
__global__ __launch_bounds__(256) void merge2(const unsigned short* __restrict__ Wp,
                                              const unsigned short* __restrict__ xt,
                                              const float* __restrict__ bias,
                                              float* __restrict__ out) {
  __shared__ unsigned short At[128 * 64];  // 16 KB, swizzled
  __shared__ unsigned short Bt[128 * 64];  // 16 KB, swizzled
  const int tid = threadIdx.x;
  const int w = tid >> 6, lane = tid & 63;
  const int quad = lane >> 4, l16 = lane & 15;
  const int wx = w & 1, wy = w >> 1;
  const int n0 = blockIdx.x * 128, o0 = blockIdx.y * 128, b = blockIdx.z;
  const int srow = w * 8 + (lane >> 3), scb = lane & 7;
  const unsigned short* Bbase = xt + (size_t)b * ((size_t)NSEQ * CCH);

  f32x4 acc[4][4];
#pragma unroll
  for (int ot = 0; ot < 4; ++ot)
#pragma unroll
    for (int nt = 0; nt < 4; ++nt) acc[ot][nt] = (f32x4){0.f, 0.f, 0.f, 0.f};

  for (int c0 = 0; c0 < CCH; c0 += 64) {
    __syncthreads();
#pragma unroll
    for (int i = 0; i < 4; ++i) {
      int row = i * 32 + srow;
      int cbl = scb ^ (row & 7);
      gld16(Wp + (size_t)(o0 + row) * CCH + c0 + cbl * 8, &At[(i * 32 + w * 8) * 64]);
      gld16(Bbase + (size_t)(n0 + row) * CCH + c0 + cbl * 8, &Bt[(i * 32 + w * 8) * 64]);
    }
    __syncthreads();
#pragma unroll
    for (int ks = 0; ks < 2; ++ks) {
      bf16x8 aW[4], bX[4];
      int phys = ((ks * 4 + quad) ^ (l16 & 7)) * 8;
#pragma unroll
      for (int t = 0; t < 4; ++t) {
        aW[t] = *(const bf16x8*)&At[(wy * 64 + t * 16 + l16) * 64 + phys];
        bX[t] = *(const bf16x8*)&Bt[(wx * 64 + t * 16 + l16) * 64 + phys];
      }
#pragma unroll
      for (int ot = 0; ot < 4; ++ot)
#pragma unroll
        for (int nt = 0; nt < 4; ++nt)
          acc[ot][nt] = __builtin_amdgcn_mfma_f32_16x16x32_bf16(aW[ot], bX[nt], acc[ot][nt], 0, 0, 0);
    }
  }

#pragma unroll
  for (int ot = 0; ot < 4; ++ot)
#pragma unroll
    for (int r = 0; r < 4; ++r) {
      int o = o0 + wy * 64 + ot * 16 + quad * 4 + r;
      float bi = bias[o];
#pragma unroll
      for (int nt = 0; nt < 4; ++nt)
        out[(size_t)b * ((size_t)CCH * NSEQ) + (size_t)o * NSEQ + n0 + wx * 64 + nt * 16 + l16] =
            acc[ot][nt][r] + bi;
    }
}

extern "C" void kernel_launch(void* const* d_in, const int* in_sizes, int n_in,
                              void* d_out, int out_size, void* d_ws, size_t ws_size,
                              hipStream_t stream) {
  const float* q = (const float*)d_in[0];
  const float* k = (const float*)d_in[1];
  const float* v = (const float*)d_in[2];
  const float* W = (const float*)d_in[3];
  const float* bias = (const float*)d_in[4];
  float* out = (float*)d_out;

  // ws layout (ushort units): Wp 1Mi | xt 4Mi | Qt 4Mi | Kt 4Mi | Vb 4Mi = 34 MiB
  unsigned short* Wp = (unsigned short*)d_ws;
  unsigned short* xt = Wp + (1u << 20);
  unsigned short* Qt = xt + (4u << 20);
  unsigned short* Kt = Qt + (4u << 20);
  unsigned short* Vb = Kt + (4u << 20);

  hipLaunchKernelGGL(prep_w, dim3(4096), dim3(256), 0, stream, W, Wp);
  hipLaunchKernelGGL(conv_v, dim3(4096), dim3(256), 0, stream, v, Vb);
  hipLaunchKernelGGL(prep_tr, dim3(NSEQ / 64, H, BATCH * 2), dim3(256), 0, stream,
                     q, k, Qt, Kt);
  hipLaunchKernelGGL(attn3, dim3(NSEQ / 128, H, BATCH), dim3(256), 0, stream,
                     Qt, Kt, Vb, xt);
  hipLaunchKernelGGL(merge2, dim3(NSEQ / 128, CCH / 128, BATCH), dim3(256), 0, stream,
                     Wp, xt, bias, out);
}

// Round 4
// 177.936 us; speedup vs baseline: 1.9338x; 1.0767x over previous
//
#include <hip/hip_runtime.h>

// MHSA fused pipeline v4, MI355X gfx950.
// B=2, N=2048, C=1024, H=16, dim=64.
//
// v4: attn uses 32x32x16 MFMA with transposed scores St = K*Q^T; the St C-layout
// (col = n = lane&31) is PV's A-operand layout after 4 v_permlane32_swap per tile
// -> P never touches LDS. Softmax normalization deferred to an in-LDS epilogue.
// In-block m-split x2 (8 waves: 2 m-groups x 4 n-waves), partials combined in LDS.
// merge: 1-barrier double-buffered prefetch.

#define H 16
#define DIM 64
#define NSEQ 2048
#define CCH 1024
#define BATCH 2
#define DSTR (H * NSEQ)  // 32768

typedef __attribute__((ext_vector_type(8))) short bf16x8;
typedef __attribute__((ext_vector_type(4))) float f32x4;
typedef __attribute__((ext_vector_type(16))) float f32x16;
typedef __attribute__((ext_vector_type(4))) unsigned int uint32x4;

__device__ __forceinline__ unsigned short f2bf(float x) {
  unsigned int u = __builtin_bit_cast(unsigned int, x);
  u += 0x7FFFu + ((u >> 16) & 1u);  // RNE
  return (unsigned short)(u >> 16);
}

__device__ __forceinline__ unsigned int pack2bf(float a, float b) {
#if __has_builtin(__builtin_amdgcn_cvt_pk_bf16_f32)
  typedef __attribute__((ext_vector_type(2))) __bf16 bf16x2_t;
  bf16x2_t r = __builtin_amdgcn_cvt_pk_bf16_f32(a, b);
  return __builtin_bit_cast(unsigned int, r);
#else
  unsigned int ua = __builtin_bit_cast(unsigned int, a);
  unsigned int ub = __builtin_bit_cast(unsigned int, b);
  ua += 0x7FFFu + ((ua >> 16) & 1u);
  ub += 0x7FFFu + ((ub >> 16) & 1u);
  return __builtin_amdgcn_perm(ub, ua, 0x07060302u);
#endif
}

__device__ __forceinline__ float fast_exp2(float x) {
#if __has_builtin(__builtin_amdgcn_exp2f)
  return __builtin_amdgcn_exp2f(x);
#else
  return exp2f(x);
#endif
}

// Exchange high 32 lanes of a with low 32 lanes of b (MFMA C->A transpose helper).
__device__ __forceinline__ void permswap32(unsigned int& a, unsigned int& b) {
#if __has_builtin(__builtin_amdgcn_permlane32_swap)
  typedef __attribute__((ext_vector_type(2))) unsigned int uint2v;
  uint2v r = __builtin_amdgcn_permlane32_swap(a, b, false, false);
  a = r[0];
  b = r[1];
#else
  unsigned int ax = (unsigned int)__shfl_xor((int)a, 32, 64);
  unsigned int bx = (unsigned int)__shfl_xor((int)b, 32, 64);
  bool lo = (threadIdx.x & 63) < 32;
  unsigned int na = lo ? a : bx;
  unsigned int nb = lo ? ax : b;
  a = na;
  b = nb;
#endif
}

__device__ __forceinline__ void gld16(const void* g, void* l) {
  __builtin_amdgcn_global_load_lds(
      (const __attribute__((address_space(1))) unsigned int*)g,
      (__attribute__((address_space(3))) unsigned int*)l, 16, 0, 0);
}

__device__ __forceinline__ f32x16 zero16() {
  f32x16 v;
#pragma unroll
  for (int i = 0; i < 16; ++i) v[i] = 0.f;
  return v;
}

// ---------------- prep: W permute+convert ----------------
__global__ __launch_bounds__(256) void prep_w(const float* __restrict__ W,
                                              unsigned short* __restrict__ Wp) {
  int idx = blockIdx.x * 256 + threadIdx.x;
  int o = idx >> 10, cp = idx & 1023;
  int hh = cp >> 6, d = cp & 63;
  Wp[idx] = f2bf(W[o * CCH + d * H + hh]);
}

// ---------------- prep: V flat convert ----------------
__global__ __launch_bounds__(256) void conv_v(const float* __restrict__ v,
                                              unsigned short* __restrict__ Vb) {
  int idx = blockIdx.x * 256 + threadIdx.x;
  float4 x = ((const float4*)v)[idx];
  ushort4 o;
  o.x = f2bf(x.x); o.y = f2bf(x.y); o.z = f2bf(x.z); o.w = f2bf(x.w);
  ((ushort4*)Vb)[idx] = o;
}

// ---------------- prep: Q/K transpose+convert to [b][h][n][d] ----------------
__global__ __launch_bounds__(256) void prep_tr(const float* __restrict__ q,
                                               const float* __restrict__ k,
                                               unsigned short* __restrict__ Qt,
                                               unsigned short* __restrict__ Kt) {
  __shared__ unsigned short T[64][72];
  const int tid = threadIdx.x;
  const int n0 = blockIdx.x * 64;
  const int hh = blockIdx.y;
  const int b = blockIdx.z >> 1, t = blockIdx.z & 1;
  const float* src = t ? k : q;
  unsigned short* dst = t ? Kt : Qt;
  // Q scale: 1/sqrt(2048) * log2(e)
  const float scl = t ? 1.0f : (0.022097086912079608f * 1.4426950408889634f);
  const size_t base = (size_t)b * (CCH * NSEQ) + (size_t)hh * NSEQ;
#pragma unroll
  for (int it = 0; it < 4; ++it) {
    int i4 = it * 256 + tid;
    int d = i4 >> 4;
    int nn = (i4 & 15) << 2;
    float4 val = *(const float4*)(src + base + (size_t)d * DSTR + n0 + nn);
    T[nn + 0][d] = f2bf(val.x * scl);
    T[nn + 1][d] = f2bf(val.y * scl);
    T[nn + 2][d] = f2bf(val.z * scl);
    T[nn + 3][d] = f2bf(val.w * scl);
  }
  __syncthreads();
  const size_t obase = ((size_t)(b * H + hh) * NSEQ + n0) * 64;
#pragma unroll
  for (int it = 0; it < 2; ++it) {
    int idx = it * 256 + tid;
    int row = idx >> 3, cb = idx & 7;
    *(bf16x8*)(dst + obase + (size_t)row * 64 + cb * 8) = *(const bf16x8*)&T[row][cb * 8];
  }
}

// ---------------- attention v4 ----------------
// grid (8, 16, 2), block 512 (8 waves = 2 m-groups x 4 n-waves), n-block = 256.
__global__ __launch_bounds__(512, 2) void attn4(const unsigned short* __restrict__ Qt,
                                                const unsigned short* __restrict__ Kt,
                                                const unsigned short* __restrict__ Vb,
                                                unsigned short* __restrict__ xt) {
  // 64 KB K/V tiles (2 groups x 2 dbuf x {K,V} x 8KB) + 2 KB lsum; epilogue
  // reuses the K/V area as a 256x64 f32 partial-O exchange buffer.
  __shared__ __align__(16) unsigned char sbuf[65536 + 2048];
  unsigned short* KV = (unsigned short*)sbuf;
  float* lsumLDS = (float*)(sbuf + 65536);  // [2][256]
  float* Oex = (float*)sbuf;                // [256][64]

  const int tid = threadIdx.x;
  const int w = tid >> 6, lane = tid & 63;
  const int lane31 = lane & 31, hl = lane >> 5;
  const int g = w >> 2, nw = w & 3;
  const int n0 = blockIdx.x * 256;
  const int hh = blockIdx.y, b = blockIdx.z;

  const unsigned short* Qbase = Qt + ((size_t)(b * H + hh) * NSEQ + n0) * 64;
  const unsigned short* Kg = Kt + ((size_t)(b * H + hh) * NSEQ + g * 1024) * 64;
  const unsigned short* Vg = Vb + (size_t)b * (CCH * NSEQ) + (size_t)hh * NSEQ + g * 1024;

  const int r8 = lane >> 3, scb = lane & 7;

  // ---- stage Q (32 KB) with all 8 waves ----
#pragma unroll
  for (int i = 0; i < 4; ++i) {
    int row = i * 64 + w * 8 + r8;
    int cbl = scb ^ (row & 7);
    gld16(Qbase + (size_t)row * 64 + cbl * 8, KV + (i * 64 + w * 8) * 64);
  }
  __syncthreads();

  // ---- loop-invariant Q B-fragments: B[col=n=lane31][k=d] ----
  bf16x8 bQ[2][4];
#pragma unroll
  for (int nt = 0; nt < 2; ++nt)
#pragma unroll
    for (int ks = 0; ks < 4; ++ks) {
      int row = nw * 64 + nt * 32 + lane31;
      int phys = (ks * 2 + hl) ^ (row & 7);
      bQ[nt][ks] = *(const bf16x8*)(KV + (size_t)row * 64 + phys * 8);
    }
  __syncthreads();  // Q reads done; KV becomes K/V tile space

  // KV tile offset helper (shorts): [g][buf][kv] tiles of 4096
#define KVOFF(gg, bb, kk) ((((gg)*2 + (bb)) * 2 + (kk)) * 4096)

  // ---- stage K/V iter 0 into buf 0 (each group stages its own) ----
#pragma unroll
  for (int i = 0; i < 2; ++i) {
    int row = i * 32 + nw * 8 + r8;
    int cbl = scb ^ (row & 7);
    gld16(Kg + (size_t)row * 64 + cbl * 8, KV + KVOFF(g, 0, 0) + (i * 32 + nw * 8) * 64);
    gld16(Vg + (size_t)row * DSTR + cbl * 8, KV + KVOFF(g, 0, 1) + (i * 32 + nw * 8) * 64);
  }
  __syncthreads();

  f32x16 O[2][2];  // [nt][dt]
#pragma unroll
  for (int nt = 0; nt < 2; ++nt)
#pragma unroll
    for (int dt = 0; dt < 2; ++dt) O[nt][dt] = zero16();
  float lsum[2] = {0.f, 0.f};

  for (int it = 0; it < 16; ++it) {
    const int cur = it & 1;
    if (it < 15) {
      const int nxt = cur ^ 1;
      const int m0n = (it + 1) * 64;
#pragma unroll
      for (int i = 0; i < 2; ++i) {
        int row = i * 32 + nw * 8 + r8;
        int cbl = scb ^ (row & 7);
        gld16(Kg + (size_t)(m0n + row) * 64 + cbl * 8,
              KV + KVOFF(g, nxt, 0) + (i * 32 + nw * 8) * 64);
        gld16(Vg + (size_t)row * DSTR + m0n + cbl * 8,
              KV + KVOFF(g, nxt, 1) + (i * 32 + nw * 8) * 64);
      }
    }

#pragma unroll
    for (int mt = 0; mt < 2; ++mt) {
      // ---- St[m 32][n 32 x2] = K . Q^T ----
      f32x16 St[2];
      St[0] = zero16();
      St[1] = zero16();
#pragma unroll
      for (int ks = 0; ks < 4; ++ks) {
        int row = mt * 32 + lane31;
        int phys = (ks * 2 + hl) ^ (row & 7);
        bf16x8 aK = *(const bf16x8*)(KV + KVOFF(g, cur, 0) + row * 64 + phys * 8);
        St[0] = __builtin_amdgcn_mfma_f32_32x32x16_bf16(aK, bQ[0][ks], St[0], 0, 0, 0);
        St[1] = __builtin_amdgcn_mfma_f32_32x32x16_bf16(aK, bQ[1][ks], St[1], 0, 0, 0);
      }

      // ---- P = exp2(St), pack to bf16 pairs (consecutive m) ----
      unsigned int pd[2][8];
#pragma unroll
      for (int nt = 0; nt < 2; ++nt)
#pragma unroll
        for (int t = 0; t < 8; ++t) {
          float e0 = fast_exp2(St[nt][2 * t]);
          float e1 = fast_exp2(St[nt][2 * t + 1]);
          lsum[nt] += e0 + e1;
          pd[nt][t] = pack2bf(e0, e1);
        }

      // ---- C-layout -> A-layout via permlane32_swap (no LDS) ----
      unsigned int s[2][2][4];  // [nt][ms][reg]
#pragma unroll
      for (int nt = 0; nt < 2; ++nt) {
        s[nt][0][0] = pd[nt][0]; s[nt][0][2] = pd[nt][2];
        s[nt][0][1] = pd[nt][1]; s[nt][0][3] = pd[nt][3];
        s[nt][1][0] = pd[nt][4]; s[nt][1][2] = pd[nt][6];
        s[nt][1][1] = pd[nt][5]; s[nt][1][3] = pd[nt][7];
        permswap32(s[nt][0][0], s[nt][0][2]);
        permswap32(s[nt][0][1], s[nt][0][3]);
        permswap32(s[nt][1][0], s[nt][1][2]);
        permswap32(s[nt][1][1], s[nt][1][3]);
      }

      // ---- PV: O[n][d] += P[n][m] . V[d][m] ----
#pragma unroll
      for (int ms = 0; ms < 2; ++ms) {
        bf16x8 bV[2];
#pragma unroll
        for (int dt = 0; dt < 2; ++dt) {
          int row = dt * 32 + lane31;
          int phys = (mt * 4 + ms * 2 + hl) ^ (row & 7);
          bV[dt] = *(const bf16x8*)(KV + KVOFF(g, cur, 1) + row * 64 + phys * 8);
        }
#pragma unroll
        for (int nt = 0; nt < 2; ++nt) {
          bf16x8 aP = __builtin_bit_cast(
              bf16x8, (uint32x4){s[nt][ms][0], s[nt][ms][1], s[nt][ms][2], s[nt][ms][3]});
          O[nt][0] = __builtin_amdgcn_mfma_f32_32x32x16_bf16(aP, bV[0], O[nt][0], 0, 0, 0);
          O[nt][1] = __builtin_amdgcn_mfma_f32_32x32x16_bf16(aP, bV[1], O[nt][1], 0, 0, 0);
        }
      }
    }
    __syncthreads();  // prefetch drained + cur safe to overwrite next iter
  }

  // ---- epilogue: combine the two m-groups in LDS, normalize, store ----
#pragma unroll
  for (int nt = 0; nt < 2; ++nt) lsum[nt] += __shfl_xor(lsum[nt], 32, 64);
  if (hl == 0) {
#pragma unroll
    for (int nt = 0; nt < 2; ++nt)
      lsumLDS[g * 256 + nw * 64 + nt * 32 + lane31] = lsum[nt];
  }
  if (g == 1) {
#pragma unroll
    for (int nt = 0; nt < 2; ++nt)
#pragma unroll
      for (int dt = 0; dt < 2; ++dt)
#pragma unroll
        for (int r = 0; r < 16; ++r) {
          int nl = nw * 64 + nt * 32 + (r & 3) + 8 * (r >> 2) + 4 * hl;
          Oex[nl * 64 + dt * 32 + lane31] = O[nt][dt][r];
        }
  }
  __syncthreads();
  if (g == 0) {
    const size_t xb = (size_t)b * ((size_t)NSEQ * CCH);
#pragma unroll
    for (int nt = 0; nt < 2; ++nt)
#pragma unroll
      for (int rq = 0; rq < 4; ++rq) {
        int nlb = nw * 64 + nt * 32 + rq * 8 + 4 * hl;
        float4 l0 = *(const float4*)&lsumLDS[nlb];
        float4 l1 = *(const float4*)&lsumLDS[256 + nlb];
        float inv0 = 1.0f / (l0.x + l1.x);
        float inv1 = 1.0f / (l0.y + l1.y);
        float inv2 = 1.0f / (l0.z + l1.z);
        float inv3 = 1.0f / (l0.w + l1.w);
#pragma unroll
        for (int dt = 0; dt < 2; ++dt) {
          int d = dt * 32 + lane31;
#pragma unroll
          for (int rr = 0; rr < 4; ++rr) {
            int r = rq * 4 + rr;
            float val = O[nt][dt][r] + Oex[(nlb + rr) * 64 + d];
            float inv = (rr == 0) ? inv0 : (rr == 1) ? inv1 : (rr == 2) ? inv2 : inv3;
            int n = n0 + nlb + rr;
            xt[xb + (size_t)n * CCH + hh * 64 + d] = f2bf(val * inv);
          }
        }
      }
  }
#undef KVOFF
}

// ---------------- merge GEMM with dbuf prefetch ----------------
__global__ __launch_bounds__(256, 2) void merge3(const unsigned short* __restrict__ Wp,
                                                 const unsigned short* __restrict__ xt,
                                                 const float* __restrict__ bias,
                                                 float* __restrict__ out) {
  __shared__ unsigned short At[2][128 * 64];
  __shared__ unsigned short Bt[2][128 * 64];
  const int tid = threadIdx.x;
  const int w = tid >> 6, lane = tid & 63;
  const int quad = lane >> 4, l16 = lane & 15;
  const int wx = w & 1, wy = w >> 1;
  const int n0 = blockIdx.x * 128, o0 = blockIdx.y * 128, b = blockIdx.z;
  const int srow = w * 8 + (lane >> 3), scb = lane & 7;
  const unsigned short* Bbase = xt + (size_t)b * ((size_t)NSEQ * CCH);

  f32x4 acc[4][4];
#pragma unroll
  for (int ot = 0; ot < 4; ++ot)
#pragma unroll
    for (int nt = 0; nt < 4; ++nt) acc[ot][nt] = (f32x4){0.f, 0.f, 0.f, 0.f};

  // stage c0=0 into buf 0
#pragma unroll
  for (int i = 0; i < 4; ++i) {
    int row = i * 32 + srow;
    int cbl = scb ^ (row & 7);
    gld16(Wp + (size_t)(o0 + row) * CCH + cbl * 8, &At[0][(i * 32 + w * 8) * 64]);
    gld16(Bbase + (size_t)(n0 + row) * CCH + cbl * 8, &Bt[0][(i * 32 + w * 8) * 64]);
  }
  __syncthreads();

  for (int it = 0; it < 16; ++it) {
    const int cur = it & 1;
    if (it < 15) {
      const int nxt = cur ^ 1;
      const int c0 = (it + 1) * 64;
#pragma unroll
      for (int i = 0; i < 4; ++i) {
        int row = i * 32 + srow;
        int cbl = scb ^ (row & 7);
        gld16(Wp + (size_t)(o0 + row) * CCH + c0 + cbl * 8, &At[nxt][(i * 32 + w * 8) * 64]);
        gld16(Bbase + (size_t)(n0 + row) * CCH + c0 + cbl * 8, &Bt[nxt][(i * 32 + w * 8) * 64]);
      }
    }
#pragma unroll
    for (int ks = 0; ks < 2; ++ks) {
      bf16x8 aW[4], bX[4];
      int phys = ((ks * 4 + quad) ^ (l16 & 7)) * 8;
#pragma unroll
      for (int t = 0; t < 4; ++t) {
        aW[t] = *(const bf16x8*)&At[cur][(wy * 64 + t * 16 + l16) * 64 + phys];
        bX[t] = *(const bf16x8*)&Bt[cur][(wx * 64 + t * 16 + l16) * 64 + phys];
      }
#pragma unroll
      for (int ot = 0; ot < 4; ++ot)
#pragma unroll
        for (int nt = 0; nt < 4; ++nt)
          acc[ot][nt] =
              __builtin_amdgcn_mfma_f32_16x16x32_bf16(aW[ot], bX[nt], acc[ot][nt], 0, 0, 0);
    }
    __syncthreads();
  }

#pragma unroll
  for (int ot = 0; ot < 4; ++ot)
#pragma unroll
    for (int r = 0; r < 4; ++r) {
      int o = o0 + wy * 64 + ot * 16 + quad * 4 + r;
      float bi = bias[o];
#pragma unroll
      for (int nt = 0; nt < 4; ++nt)
        out[(size_t)b * ((size_t)CCH * NSEQ) + (size_t)o * NSEQ + n0 + wx * 64 + nt * 16 + l16] =
            acc[ot][nt][r] + bi;
    }
}

extern "C" void kernel_launch(void* const* d_in, const int* in_sizes, int n_in,
                              void* d_out, int out_size, void* d_ws, size_t ws_size,
                              hipStream_t stream) {
  const float* q = (const float*)d_in[0];
  const float* k = (const float*)d_in[1];
  const float* v = (const float*)d_in[2];
  const float* W = (const float*)d_in[3];
  const float* bias = (const float*)d_in[4];
  float* out = (float*)d_out;

  // ws layout (ushort units): Wp 1Mi | xt 4Mi | Qt 4Mi | Kt 4Mi | Vb 4Mi = 34 MiB
  unsigned short* Wp = (unsigned short*)d_ws;
  unsigned short* xt = Wp + (1u << 20);
  unsigned short* Qt = xt + (4u << 20);
  unsigned short* Kt = Qt + (4u << 20);
  unsigned short* Vb = Kt + (4u << 20);

  hipLaunchKernelGGL(prep_w, dim3(4096), dim3(256), 0, stream, W, Wp);
  hipLaunchKernelGGL(conv_v, dim3(4096), dim3(256), 0, stream, v, Vb);
  hipLaunchKernelGGL(prep_tr, dim3(NSEQ / 64, H, BATCH * 2), dim3(256), 0, stream,
                     q, k, Qt, Kt);
  hipLaunchKernelGGL(attn4, dim3(NSEQ / 256, H, BATCH), dim3(512), 0, stream,
                     Qt, Kt, Vb, xt);
  hipLaunchKernelGGL(merge3, dim3(NSEQ / 128, CCH / 128, BATCH), dim3(256), 0, stream,
                     Wp, xt, bias, out);
}

// Round 5
// 171.516 us; speedup vs baseline: 2.0062x; 1.0374x over previous
//
#include <hip/hip_runtime.h>

// MHSA fused pipeline v5, MI355X gfx950.
// B=2, N=2048, C=1024, H=16, dim=64.
//
// v5: (a) all prep work fused into ONE kernel (3 launches total, was 5);
// (b) attn: no m-split, n-block 128, 256-thr blocks, grid 512 = 2 blocks/CU
//     (v4 was 1 block/CU -> barrier drains had nothing to overlap with);
//     same in-register P path (St = K*Q^T 32x32, exp2, pack, permlane32_swap);
//     epilogue normalizes in-register via shuffles (no LDS exchange);
// (c) merge: 64x128 tiles, grid 512 = 2 blocks/CU, double-buffered.

#define H 16
#define NSEQ 2048
#define CCH 1024
#define BATCH 2
#define DSTR (H * NSEQ)  // 32768

typedef __attribute__((ext_vector_type(8))) short bf16x8;
typedef __attribute__((ext_vector_type(4))) float f32x4;
typedef __attribute__((ext_vector_type(16))) float f32x16;
typedef __attribute__((ext_vector_type(4))) unsigned int uint32x4;

__device__ __forceinline__ unsigned short f2bf(float x) {
  unsigned int u = __builtin_bit_cast(unsigned int, x);
  u += 0x7FFFu + ((u >> 16) & 1u);  // RNE
  return (unsigned short)(u >> 16);
}

__device__ __forceinline__ unsigned int pack2bf(float a, float b) {
#if __has_builtin(__builtin_amdgcn_cvt_pk_bf16_f32)
  typedef __attribute__((ext_vector_type(2))) __bf16 bf16x2_t;
  bf16x2_t r = __builtin_amdgcn_cvt_pk_bf16_f32(a, b);
  return __builtin_bit_cast(unsigned int, r);
#else
  unsigned int ua = __builtin_bit_cast(unsigned int, a);
  unsigned int ub = __builtin_bit_cast(unsigned int, b);
  ua += 0x7FFFu + ((ua >> 16) & 1u);
  ub += 0x7FFFu + ((ub >> 16) & 1u);
  return __builtin_amdgcn_perm(ub, ua, 0x07060302u);
#endif
}

__device__ __forceinline__ float fast_exp2(float x) {
#if __has_builtin(__builtin_amdgcn_exp2f)
  return __builtin_amdgcn_exp2f(x);
#else
  return exp2f(x);
#endif
}

__device__ __forceinline__ void permswap32(unsigned int& a, unsigned int& b) {
#if __has_builtin(__builtin_amdgcn_permlane32_swap)
  typedef __attribute__((ext_vector_type(2))) unsigned int uint2v;
  uint2v r = __builtin_amdgcn_permlane32_swap(a, b, false, false);
  a = r[0];
  b = r[1];
#else
  unsigned int ax = (unsigned int)__shfl_xor((int)a, 32, 64);
  unsigned int bx = (unsigned int)__shfl_xor((int)b, 32, 64);
  bool lo = (threadIdx.x & 63) < 32;
  unsigned int na = lo ? a : bx;
  unsigned int nb = lo ? ax : b;
  a = na;
  b = nb;
#endif
}

__device__ __forceinline__ void gld16(const void* g, void* l) {
  __builtin_amdgcn_global_load_lds(
      (const __attribute__((address_space(1))) unsigned int*)g,
      (__attribute__((address_space(3))) unsigned int*)l, 16, 0, 0);
}

__device__ __forceinline__ f32x16 zero16() {
  f32x16 v;
#pragma unroll
  for (int i = 0; i < 16; ++i) v[i] = 0.f;
  return v;
}

// ---------------- fused prep: W permute | V convert | Q/K transpose ----------------
// grid: [0,1024) W-rows | [1024,5120) V float4 | [5120,7168) QK 64-n tiles
__global__ __launch_bounds__(256) void prep_all(const float* __restrict__ W,
                                                const float* __restrict__ v,
                                                const float* __restrict__ q,
                                                const float* __restrict__ k,
                                                unsigned short* __restrict__ Wp,
                                                unsigned short* __restrict__ Vb,
                                                unsigned short* __restrict__ Qt,
                                                unsigned short* __restrict__ Kt) {
  __shared__ unsigned short T[64][72];
  const int bid = blockIdx.x, tid = threadIdx.x;

  if (bid < 1024) {
    // Wp[o][c'=hh*64+d] = bf16(W[o][d*16+hh]); reads L1-local, writes coalesced
    const int o = bid;
    const int cp = tid * 4;
    const int hh = cp >> 6;
    const int d0 = cp & 63;
    const float* Wr = W + (size_t)o * CCH;
    ushort4 ov;
    ov.x = f2bf(Wr[(d0 + 0) * H + hh]);
    ov.y = f2bf(Wr[(d0 + 1) * H + hh]);
    ov.z = f2bf(Wr[(d0 + 2) * H + hh]);
    ov.w = f2bf(Wr[(d0 + 3) * H + hh]);
    *(ushort4*)&Wp[(size_t)o * CCH + cp] = ov;
  } else if (bid < 5120) {
    // V flat convert
    int idx = (bid - 1024) * 256 + tid;
    float4 x = ((const float4*)v)[idx];
    ushort4 o;
    o.x = f2bf(x.x); o.y = f2bf(x.y); o.z = f2bf(x.z); o.w = f2bf(x.w);
    ((ushort4*)Vb)[idx] = o;
  } else {
    // Q/K transpose+convert to [b][h][n][d]
    const int lbid = bid - 5120;
    const int n0 = (lbid & 31) * 64;
    const int hh = (lbid >> 5) & 15;
    const int zz = lbid >> 9;
    const int b = zz >> 1, t = zz & 1;
    const float* src = t ? k : q;
    unsigned short* dst = t ? Kt : Qt;
    // Q scale: 1/sqrt(2048) * log2(e)  (softmax exp -> exp2)
    const float scl = t ? 1.0f : (0.022097086912079608f * 1.4426950408889634f);
    const size_t base = (size_t)b * (CCH * NSEQ) + (size_t)hh * NSEQ;
#pragma unroll
    for (int it = 0; it < 4; ++it) {
      int i4 = it * 256 + tid;
      int d = i4 >> 4;
      int nn = (i4 & 15) << 2;
      float4 val = *(const float4*)(src + base + (size_t)d * DSTR + n0 + nn);
      T[nn + 0][d] = f2bf(val.x * scl);
      T[nn + 1][d] = f2bf(val.y * scl);
      T[nn + 2][d] = f2bf(val.z * scl);
      T[nn + 3][d] = f2bf(val.w * scl);
    }
    __syncthreads();
    const size_t obase = ((size_t)(b * H + hh) * NSEQ + n0) * 64;
#pragma unroll
    for (int it = 0; it < 2; ++it) {
      int idx = it * 256 + tid;
      int row = idx >> 3, cb = idx & 7;
      *(bf16x8*)(dst + obase + (size_t)row * 64 + cb * 8) = *(const bf16x8*)&T[row][cb * 8];
    }
  }
}

// ---------------- attention v5 ----------------
// grid (16,16,2) = 512 blocks (2/CU), block 256 (4 waves x 32 n-rows), n-block 128.
__global__ __launch_bounds__(256) void attn5(const unsigned short* __restrict__ Qt,
                                             const unsigned short* __restrict__ Kt,
                                             const unsigned short* __restrict__ Vb,
                                             unsigned short* __restrict__ xt) {
  // 32 KB: [buf][{K,V}] 64x64 tiles; Q (16 KB) staged into buf0 area pre-loop
  __shared__ __align__(16) unsigned short S[4 * 4096];
#define KS(bb) (S + (bb) * 8192)
#define VS(bb) (S + (bb) * 8192 + 4096)

  const int tid = threadIdx.x;
  const int w = tid >> 6, lane = tid & 63;
  const int lane31 = lane & 31, hl = lane >> 5;
  const int n0 = blockIdx.x * 128;
  const int hh = blockIdx.y, b = blockIdx.z;

  const unsigned short* Qbase = Qt + ((size_t)(b * H + hh) * NSEQ + n0) * 64;
  const unsigned short* Kbase = Kt + ((size_t)(b * H + hh) * NSEQ) * 64;
  const unsigned short* Vbase = Vb + (size_t)b * (CCH * NSEQ) + (size_t)hh * NSEQ;

  const int r8 = lane >> 3, scb = lane & 7;

  // ---- stage Q (128x64, swizzled phys cb = cb ^ (row&7)) into S[0..8191] ----
#pragma unroll
  for (int i = 0; i < 4; ++i) {
    int row = i * 32 + w * 8 + r8;
    int cbl = scb ^ (row & 7);
    gld16(Qbase + (size_t)row * 64 + cbl * 8, S + (i * 32 + w * 8) * 64);
  }
  __syncthreads();

  // ---- loop-invariant Q B-fragments: B[col=n=lane31][k=d] ----
  bf16x8 bQ[4];
#pragma unroll
  for (int ks = 0; ks < 4; ++ks) {
    int row = w * 32 + lane31;
    int phys = (ks * 2 + hl) ^ (row & 7);
    bQ[ks] = *(const bf16x8*)(S + (size_t)row * 64 + phys * 8);
  }
  __syncthreads();  // Q reads done; S becomes K/V tile space

  // ---- stage K/V tile 0 into buf 0 ----
#pragma unroll
  for (int i = 0; i < 2; ++i) {
    int row = i * 32 + w * 8 + r8;
    int cbl = scb ^ (row & 7);
    gld16(Kbase + (size_t)row * 64 + cbl * 8, KS(0) + (i * 32 + w * 8) * 64);
    gld16(Vbase + (size_t)row * DSTR + cbl * 8, VS(0) + (i * 32 + w * 8) * 64);
  }
  __syncthreads();

  f32x16 O[2];  // [dt]; C-layout: col = d = dt*32+lane31, regs = n-rows
  O[0] = zero16();
  O[1] = zero16();
  float lsum = 0.f;  // per-lane: col n = lane31, rows split across hl

  for (int it = 0; it < 32; ++it) {
    const int cur = it & 1;
    if (it < 31) {
      const int nxt = cur ^ 1;
      const int m0n = (it + 1) * 64;
#pragma unroll
      for (int i = 0; i < 2; ++i) {
        int row = i * 32 + w * 8 + r8;
        int cbl = scb ^ (row & 7);
        gld16(Kbase + (size_t)(m0n + row) * 64 + cbl * 8, KS(nxt) + (i * 32 + w * 8) * 64);
        gld16(Vbase + (size_t)row * DSTR + m0n + cbl * 8, VS(nxt) + (i * 32 + w * 8) * 64);
      }
    }

#pragma unroll
    for (int mt = 0; mt < 2; ++mt) {
      // St[m 32][n 32] = K . Q^T
      f32x16 St = zero16();
#pragma unroll
      for (int ks = 0; ks < 4; ++ks) {
        int row = mt * 32 + lane31;
        int phys = (ks * 2 + hl) ^ (row & 7);
        bf16x8 aK = *(const bf16x8*)(KS(cur) + row * 64 + phys * 8);
        St = __builtin_amdgcn_mfma_f32_32x32x16_bf16(aK, bQ[ks], St, 0, 0, 0);
      }

      // P = exp2(St) (scale*log2e pre-folded into Q), pack consecutive-m pairs
      unsigned int pd[8];
#pragma unroll
      for (int t = 0; t < 8; ++t) {
        float e0 = fast_exp2(St[2 * t]);
        float e1 = fast_exp2(St[2 * t + 1]);
        lsum += e0 + e1;
        pd[t] = pack2bf(e0, e1);
      }

      // C-layout -> A-layout in-register
      unsigned int s0[4] = {pd[0], pd[1], pd[2], pd[3]};
      unsigned int s1[4] = {pd[4], pd[5], pd[6], pd[7]};
      permswap32(s0[0], s0[2]);
      permswap32(s0[1], s0[3]);
      permswap32(s1[0], s1[2]);
      permswap32(s1[1], s1[3]);

      // PV: O[n][d] += P[n][m] . V[d][m]
#pragma unroll
      for (int ms = 0; ms < 2; ++ms) {
        bf16x8 bV[2];
#pragma unroll
        for (int dt = 0; dt < 2; ++dt) {
          int row = dt * 32 + lane31;
          int phys = (mt * 4 + ms * 2 + hl) ^ (row & 7);
          bV[dt] = *(const bf16x8*)(VS(cur) + row * 64 + phys * 8);
        }
        const unsigned int* sp = ms ? s1 : s0;
        bf16x8 aP = __builtin_bit_cast(bf16x8, (uint32x4){sp[0], sp[1], sp[2], sp[3]});
        O[0] = __builtin_amdgcn_mfma_f32_32x32x16_bf16(aP, bV[0], O[0], 0, 0, 0);
        O[1] = __builtin_amdgcn_mfma_f32_32x32x16_bf16(aP, bV[1], O[1], 0, 0, 0);
      }
    }
    __syncthreads();  // prefetch drained + cur safe to overwrite
  }

  // ---- epilogue: combine hl halves of lsum, per-reg inv via shuffle, store ----
  lsum += __shfl_xor(lsum, 32, 64);
  float linv = 1.0f / lsum;  // valid at lane = col n (both halves)

  const size_t xb = (size_t)b * ((size_t)NSEQ * CCH);
#pragma unroll
  for (int r = 0; r < 16; ++r) {
    int nl = (r & 3) + 8 * (r >> 2) + 4 * hl;  // C/D row mapping (32x32)
    float inv = __shfl(linv, nl, 64);
    int n = n0 + w * 32 + nl;
    size_t rowb = xb + (size_t)n * CCH + hh * 64;
    xt[rowb + lane31] = f2bf(O[0][r] * inv);
    xt[rowb + 32 + lane31] = f2bf(O[1][r] * inv);
  }
#undef KS
#undef VS
}

// ---------------- merge GEMM: 64(o) x 128(n) tiles, dbuf, grid 512 ----------------
__global__ __launch_bounds__(256) void merge4(const unsigned short* __restrict__ Wp,
                                              const unsigned short* __restrict__ xt,
                                              const float* __restrict__ bias,
                                              float* __restrict__ out) {
  __shared__ unsigned short At[2][64 * 64];   // 2 x 8 KB
  __shared__ unsigned short Bt[2][128 * 64];  // 2 x 16 KB
  const int tid = threadIdx.x;
  const int w = tid >> 6, lane = tid & 63;
  const int quad = lane >> 4, l16 = lane & 15;
  const int n0 = blockIdx.x * 128, o0 = blockIdx.y * 64, b = blockIdx.z;
  const int srow = w * 8 + (lane >> 3), scb = lane & 7;
  const unsigned short* Bbase = xt + (size_t)b * ((size_t)NSEQ * CCH);

  f32x4 acc[4][2];  // [ot][nt]: o = ot*16+quad*4+r, n = w*32 + nt*16 + l16
#pragma unroll
  for (int ot = 0; ot < 4; ++ot)
#pragma unroll
    for (int nt = 0; nt < 2; ++nt) acc[ot][nt] = (f32x4){0.f, 0.f, 0.f, 0.f};

  // stage c0=0 into buf 0
#pragma unroll
  for (int i = 0; i < 2; ++i) {
    int row = i * 32 + srow;
    int cbl = scb ^ (row & 7);
    gld16(Wp + (size_t)(o0 + row) * CCH + cbl * 8, &At[0][(i * 32 + w * 8) * 64]);
  }
#pragma unroll
  for (int i = 0; i < 4; ++i) {
    int row = i * 32 + srow;
    int cbl = scb ^ (row & 7);
    gld16(Bbase + (size_t)(n0 + row) * CCH + cbl * 8, &Bt[0][(i * 32 + w * 8) * 64]);
  }
  __syncthreads();

  for (int it = 0; it < 16; ++it) {
    const int cur = it & 1;
    if (it < 15) {
      const int nxt = cur ^ 1;
      const int c0 = (it + 1) * 64;
#pragma unroll
      for (int i = 0; i < 2; ++i) {
        int row = i * 32 + srow;
        int cbl = scb ^ (row & 7);
        gld16(Wp + (size_t)(o0 + row) * CCH + c0 + cbl * 8, &At[nxt][(i * 32 + w * 8) * 64]);
      }
#pragma unroll
      for (int i = 0; i < 4; ++i) {
        int row = i * 32 + srow;
        int cbl = scb ^ (row & 7);
        gld16(Bbase + (size_t)(n0 + row) * CCH + c0 + cbl * 8, &Bt[nxt][(i * 32 + w * 8) * 64]);
      }
    }
#pragma unroll
    for (int ks = 0; ks < 2; ++ks) {
      int phys = ((ks * 4 + quad) ^ (l16 & 7)) * 8;
      bf16x8 aW[4], bX[2];
#pragma unroll
      for (int ot = 0; ot < 4; ++ot)
        aW[ot] = *(const bf16x8*)&At[cur][(ot * 16 + l16) * 64 + phys];
#pragma unroll
      for (int nt = 0; nt < 2; ++nt)
        bX[nt] = *(const bf16x8*)&Bt[cur][(w * 32 + nt * 16 + l16) * 64 + phys];
#pragma unroll
      for (int ot = 0; ot < 4; ++ot)
#pragma unroll
        for (int nt = 0; nt < 2; ++nt)
          acc[ot][nt] =
              __builtin_amdgcn_mfma_f32_16x16x32_bf16(aW[ot], bX[nt], acc[ot][nt], 0, 0, 0);
    }
    __syncthreads();
  }

#pragma unroll
  for (int ot = 0; ot < 4; ++ot) {
    float4 bi = *(const float4*)&bias[o0 + ot * 16 + quad * 4];
#pragma unroll
    for (int r = 0; r < 4; ++r) {
      int o = o0 + ot * 16 + quad * 4 + r;
      float br = (r == 0) ? bi.x : (r == 1) ? bi.y : (r == 2) ? bi.z : bi.w;
#pragma unroll
      for (int nt = 0; nt < 2; ++nt)
        out[(size_t)b * ((size_t)CCH * NSEQ) + (size_t)o * NSEQ + n0 + w * 32 + nt * 16 + l16] =
            acc[ot][nt][r] + br;
    }
  }
}

extern "C" void kernel_launch(void* const* d_in, const int* in_sizes, int n_in,
                              void* d_out, int out_size, void* d_ws, size_t ws_size,
                              hipStream_t stream) {
  const float* q = (const float*)d_in[0];
  const float* k = (const float*)d_in[1];
  const float* v = (const float*)d_in[2];
  const float* W = (const float*)d_in[3];
  const float* bias = (const float*)d_in[4];
  float* out = (float*)d_out;

  // ws layout (ushort units): Wp 1Mi | xt 4Mi | Qt 4Mi | Kt 4Mi | Vb 4Mi = 34 MiB
  unsigned short* Wp = (unsigned short*)d_ws;
  unsigned short* xt = Wp + (1u << 20);
  unsigned short* Qt = xt + (4u << 20);
  unsigned short* Kt = Qt + (4u << 20);
  unsigned short* Vb = Kt + (4u << 20);

  hipLaunchKernelGGL(prep_all, dim3(7168), dim3(256), 0, stream, W, v, q, k, Wp, Vb, Qt, Kt);
  hipLaunchKernelGGL(attn5, dim3(NSEQ / 128, H, BATCH), dim3(256), 0, stream, Qt, Kt, Vb, xt);
  hipLaunchKernelGGL(merge4, dim3(NSEQ / 128, CCH / 64, BATCH), dim3(256), 0, stream,
                     Wp, xt, bias, out);
}

// Round 6
// 160.326 us; speedup vs baseline: 2.1462x; 1.0698x over previous
//
#include <hip/hip_runtime.h>

// MHSA fused pipeline v6, MI355X gfx950.
// B=2, N=2048, C=1024, H=16, dim=64.
//
// v6: attn = v4's in-block m-split (2 groups x 1024 m) but n-block 128 and
// grid 512 -> 2 blocks/CU -> 16 waves/CU (4/SIMD), double v4/v5's residency.
// n-parallelism alone caps at 8 waves/CU (65536 rows / 32 per wave); the
// m-split is the only path to more co-resident waves. merge: 64x64 tiles,
// grid 1024 -> 4 blocks/CU. prep unchanged.

#define H 16
#define NSEQ 2048
#define CCH 1024
#define BATCH 2
#define DSTR (H * NSEQ)  // 32768

typedef __attribute__((ext_vector_type(8))) short bf16x8;
typedef __attribute__((ext_vector_type(4))) float f32x4;
typedef __attribute__((ext_vector_type(16))) float f32x16;
typedef __attribute__((ext_vector_type(4))) unsigned int uint32x4;

__device__ __forceinline__ unsigned short f2bf(float x) {
  unsigned int u = __builtin_bit_cast(unsigned int, x);
  u += 0x7FFFu + ((u >> 16) & 1u);  // RNE
  return (unsigned short)(u >> 16);
}

__device__ __forceinline__ unsigned int pack2bf(float a, float b) {
#if __has_builtin(__builtin_amdgcn_cvt_pk_bf16_f32)
  typedef __attribute__((ext_vector_type(2))) __bf16 bf16x2_t;
  bf16x2_t r = __builtin_amdgcn_cvt_pk_bf16_f32(a, b);
  return __builtin_bit_cast(unsigned int, r);
#else
  unsigned int ua = __builtin_bit_cast(unsigned int, a);
  unsigned int ub = __builtin_bit_cast(unsigned int, b);
  ua += 0x7FFFu + ((ua >> 16) & 1u);
  ub += 0x7FFFu + ((ub >> 16) & 1u);
  return __builtin_amdgcn_perm(ub, ua, 0x07060302u);
#endif
}

__device__ __forceinline__ float fast_exp2(float x) {
#if __has_builtin(__builtin_amdgcn_exp2f)
  return __builtin_amdgcn_exp2f(x);
#else
  return exp2f(x);
#endif
}

__device__ __forceinline__ void permswap32(unsigned int& a, unsigned int& b) {
#if __has_builtin(__builtin_amdgcn_permlane32_swap)
  typedef __attribute__((ext_vector_type(2))) unsigned int uint2v;
  uint2v r = __builtin_amdgcn_permlane32_swap(a, b, false, false);
  a = r[0];
  b = r[1];
#else
  unsigned int ax = (unsigned int)__shfl_xor((int)a, 32, 64);
  unsigned int bx = (unsigned int)__shfl_xor((int)b, 32, 64);
  bool lo = (threadIdx.x & 63) < 32;
  unsigned int na = lo ? a : bx;
  unsigned int nb = lo ? ax : b;
  a = na;
  b = nb;
#endif
}

__device__ __forceinline__ void gld16(const void* g, void* l) {
  __builtin_amdgcn_global_load_lds(
      (const __attribute__((address_space(1))) unsigned int*)g,
      (__attribute__((address_space(3))) unsigned int*)l, 16, 0, 0);
}

__device__ __forceinline__ f32x16 zero16() {
  f32x16 v;
#pragma unroll
  for (int i = 0; i < 16; ++i) v[i] = 0.f;
  return v;
}

// ---------------- fused prep: W permute | V convert | Q/K transpose ----------------
__global__ __launch_bounds__(256) void prep_all(const float* __restrict__ W,
                                                const float* __restrict__ v,
                                                const float* __restrict__ q,
                                                const float* __restrict__ k,
                                                unsigned short* __restrict__ Wp,
                                                unsigned short* __restrict__ Vb,
                                                unsigned short* __restrict__ Qt,
                                                unsigned short* __restrict__ Kt) {
  __shared__ unsigned short T[64][72];
  const int bid = blockIdx.x, tid = threadIdx.x;

  if (bid < 1024) {
    const int o = bid;
    const int cp = tid * 4;
    const int hh = cp >> 6;
    const int d0 = cp & 63;
    const float* Wr = W + (size_t)o * CCH;
    ushort4 ov;
    ov.x = f2bf(Wr[(d0 + 0) * H + hh]);
    ov.y = f2bf(Wr[(d0 + 1) * H + hh]);
    ov.z = f2bf(Wr[(d0 + 2) * H + hh]);
    ov.w = f2bf(Wr[(d0 + 3) * H + hh]);
    *(ushort4*)&Wp[(size_t)o * CCH + cp] = ov;
  } else if (bid < 5120) {
    int idx = (bid - 1024) * 256 + tid;
    float4 x = ((const float4*)v)[idx];
    ushort4 o;
    o.x = f2bf(x.x); o.y = f2bf(x.y); o.z = f2bf(x.z); o.w = f2bf(x.w);
    ((ushort4*)Vb)[idx] = o;
  } else {
    const int lbid = bid - 5120;
    const int n0 = (lbid & 31) * 64;
    const int hh = (lbid >> 5) & 15;
    const int zz = lbid >> 9;
    const int b = zz >> 1, t = zz & 1;
    const float* src = t ? k : q;
    unsigned short* dst = t ? Kt : Qt;
    // Q scale: 1/sqrt(2048) * log2(e)  (softmax exp -> exp2)
    const float scl = t ? 1.0f : (0.022097086912079608f * 1.4426950408889634f);
    const size_t base = (size_t)b * (CCH * NSEQ) + (size_t)hh * NSEQ;
#pragma unroll
    for (int it = 0; it < 4; ++it) {
      int i4 = it * 256 + tid;
      int d = i4 >> 4;
      int nn = (i4 & 15) << 2;
      float4 val = *(const float4*)(src + base + (size_t)d * DSTR + n0 + nn);
      T[nn + 0][d] = f2bf(val.x * scl);
      T[nn + 1][d] = f2bf(val.y * scl);
      T[nn + 2][d] = f2bf(val.z * scl);
      T[nn + 3][d] = f2bf(val.w * scl);
    }
    __syncthreads();
    const size_t obase = ((size_t)(b * H + hh) * NSEQ + n0) * 64;
#pragma unroll
    for (int it = 0; it < 2; ++it) {
      int idx = it * 256 + tid;
      int row = idx >> 3, cb = idx & 7;
      *(bf16x8*)(dst + obase + (size_t)row * 64 + cb * 8) = *(const bf16x8*)&T[row][cb * 8];
    }
  }
}

// ---------------- attention v6 ----------------
// grid (16,16,2) = 512 blocks (2/CU), block 512 = 8 waves: g = m-group (2 x 1024 m),
// nw = n-wave (4 x 32 rows). 16 waves/CU resident.
__global__ __launch_bounds__(512, 4) void attn6(const unsigned short* __restrict__ Qt,
                                                const unsigned short* __restrict__ Kt,
                                                const unsigned short* __restrict__ Vb,
                                                unsigned short* __restrict__ xt) {
  // 64 KB K/V tiles ([g][buf][kv] x 8 KB) + 1 KB lsum; epilogue reuses KV
  // area as Oex[128][64] f32 (32 KB).
  __shared__ __align__(16) unsigned char sbuf[65536 + 1024];
  unsigned short* KV = (unsigned short*)sbuf;
  float* lsumLDS = (float*)(sbuf + 65536);  // [2][128]
  float* Oex = (float*)sbuf;                // [128][64]

  const int tid = threadIdx.x;
  const int w = tid >> 6, lane = tid & 63;
  const int lane31 = lane & 31, hl = lane >> 5;
  const int g = w >> 2, nw = w & 3;
  const int n0 = blockIdx.x * 128;
  const int hh = blockIdx.y, b = blockIdx.z;

  const unsigned short* Qbase = Qt + ((size_t)(b * H + hh) * NSEQ + n0) * 64;
  const unsigned short* Kg = Kt + ((size_t)(b * H + hh) * NSEQ + g * 1024) * 64;
  const unsigned short* Vg = Vb + (size_t)b * (CCH * NSEQ) + (size_t)hh * NSEQ + g * 1024;

  const int r8 = lane >> 3, scb = lane & 7;

#define KVOFF(gg, bb, kk) ((((gg)*2 + (bb)) * 2 + (kk)) * 4096)

  // ---- stage Q (128x64 = 16 KB, swizzled) into the KV area, all 8 waves ----
#pragma unroll
  for (int i = 0; i < 2; ++i) {
    int row = i * 64 + w * 8 + r8;
    int cbl = scb ^ (row & 7);
    gld16(Qbase + (size_t)row * 64 + cbl * 8, KV + (i * 64 + w * 8) * 64);
  }
  __syncthreads();

  // ---- loop-invariant Q B-fragments: B[col=n=lane31][k=d] ----
  bf16x8 bQ[4];
#pragma unroll
  for (int ks = 0; ks < 4; ++ks) {
    int row = nw * 32 + lane31;
    int phys = (ks * 2 + hl) ^ (row & 7);
    bQ[ks] = *(const bf16x8*)(KV + (size_t)row * 64 + phys * 8);
  }
  __syncthreads();  // Q reads done; KV becomes K/V tile space

  // ---- stage K/V iter 0 into buf 0 (each group its own m-range) ----
#pragma unroll
  for (int i = 0; i < 2; ++i) {
    int row = i * 32 + nw * 8 + r8;
    int cbl = scb ^ (row & 7);
    gld16(Kg + (size_t)row * 64 + cbl * 8, KV + KVOFF(g, 0, 0) + (i * 32 + nw * 8) * 64);
    gld16(Vg + (size_t)row * DSTR + cbl * 8, KV + KVOFF(g, 0, 1) + (i * 32 + nw * 8) * 64);
  }
  __syncthreads();

  f32x16 O[2];  // [dt]; col = d = dt*32+lane31, regs = n-rows
  O[0] = zero16();
  O[1] = zero16();
  float lsum = 0.f;

  for (int it = 0; it < 16; ++it) {
    const int cur = it & 1;
    if (it < 15) {
      const int nxt = cur ^ 1;
      const int m0n = (it + 1) * 64;
#pragma unroll
      for (int i = 0; i < 2; ++i) {
        int row = i * 32 + nw * 8 + r8;
        int cbl = scb ^ (row & 7);
        gld16(Kg + (size_t)(m0n + row) * 64 + cbl * 8,
              KV + KVOFF(g, nxt, 0) + (i * 32 + nw * 8) * 64);
        gld16(Vg + (size_t)row * DSTR + m0n + cbl * 8,
              KV + KVOFF(g, nxt, 1) + (i * 32 + nw * 8) * 64);
      }
    }

#pragma unroll
    for (int mt = 0; mt < 2; ++mt) {
      // St[m 32][n 32] = K . Q^T
      f32x16 St = zero16();
#pragma unroll
      for (int ks = 0; ks < 4; ++ks) {
        int row = mt * 32 + lane31;
        int phys = (ks * 2 + hl) ^ (row & 7);
        bf16x8 aK = *(const bf16x8*)(KV + KVOFF(g, cur, 0) + row * 64 + phys * 8);
        St = __builtin_amdgcn_mfma_f32_32x32x16_bf16(aK, bQ[ks], St, 0, 0, 0);
      }

      // P = exp2(St) (scale*log2e folded into Q), pack consecutive-m pairs
      unsigned int pd[8];
#pragma unroll
      for (int t = 0; t < 8; ++t) {
        float e0 = fast_exp2(St[2 * t]);
        float e1 = fast_exp2(St[2 * t + 1]);
        lsum += e0 + e1;
        pd[t] = pack2bf(e0, e1);
      }

      // C-layout -> A-layout in-register
      unsigned int s0[4] = {pd[0], pd[1], pd[2], pd[3]};
      unsigned int s1[4] = {pd[4], pd[5], pd[6], pd[7]};
      permswap32(s0[0], s0[2]);
      permswap32(s0[1], s0[3]);
      permswap32(s1[0], s1[2]);
      permswap32(s1[1], s1[3]);

      // PV: O[n][d] += P[n][m] . V[d][m]
#pragma unroll
      for (int ms = 0; ms < 2; ++ms) {
        bf16x8 bV[2];
#pragma unroll
        for (int dt = 0; dt < 2; ++dt) {
          int row = dt * 32 + lane31;
          int phys = (mt * 4 + ms * 2 + hl) ^ (row & 7);
          bV[dt] = *(const bf16x8*)(KV + KVOFF(g, cur, 1) + row * 64 + phys * 8);
        }
        const unsigned int* sp = ms ? s1 : s0;
        bf16x8 aP = __builtin_bit_cast(bf16x8, (uint32x4){sp[0], sp[1], sp[2], sp[3]});
        O[0] = __builtin_amdgcn_mfma_f32_32x32x16_bf16(aP, bV[0], O[0], 0, 0, 0);
        O[1] = __builtin_amdgcn_mfma_f32_32x32x16_bf16(aP, bV[1], O[1], 0, 0, 0);
      }
    }
    __syncthreads();
  }

  // ---- epilogue: combine the two m-groups in LDS, normalize, store ----
  lsum += __shfl_xor(lsum, 32, 64);
  if (hl == 0) lsumLDS[g * 128 + nw * 32 + lane31] = lsum;
  if (g == 1) {
#pragma unroll
    for (int dt = 0; dt < 2; ++dt)
#pragma unroll
      for (int r = 0; r < 16; ++r) {
        int nl = nw * 32 + (r & 3) + 8 * (r >> 2) + 4 * hl;
        Oex[nl * 64 + dt * 32 + lane31] = O[dt][r];
      }
  }
  __syncthreads();
  if (g == 0) {
    const size_t xb = (size_t)b * ((size_t)NSEQ * CCH);
#pragma unroll
    for (int rq = 0; rq < 4; ++rq) {
      int nlb = nw * 32 + rq * 8 + 4 * hl;
      float4 l0 = *(const float4*)&lsumLDS[nlb];
      float4 l1 = *(const float4*)&lsumLDS[128 + nlb];
      float inv0 = 1.0f / (l0.x + l1.x);
      float inv1 = 1.0f / (l0.y + l1.y);
      float inv2 = 1.0f / (l0.z + l1.z);
      float inv3 = 1.0f / (l0.w + l1.w);
#pragma unroll
      for (int dt = 0; dt < 2; ++dt) {
        int d = dt * 32 + lane31;
#pragma unroll
        for (int rr = 0; rr < 4; ++rr) {
          int r = rq * 4 + rr;
          float val = O[dt][r] + Oex[(nlb + rr) * 64 + d];
          float inv = (rr == 0) ? inv0 : (rr == 1) ? inv1 : (rr == 2) ? inv2 : inv3;
          int n = n0 + nlb + rr;
          xt[xb + (size_t)n * CCH + hh * 64 + d] = f2bf(val * inv);
        }
      }
    }
  }
#undef KVOFF
}

// ---------------- merge GEMM: 64x64 tiles, grid 1024 (4 blocks/CU), dbuf ----------------
__global__ __launch_bounds__(256) void merge5(const unsigned short* __restrict__ Wp,
                                              const unsigned short* __restrict__ xt,
                                              const float* __restrict__ bias,
                                              float* __restrict__ out) {
  __shared__ unsigned short At[2][64 * 64];  // 2 x 8 KB
  __shared__ unsigned short Bt[2][64 * 64];  // 2 x 8 KB
  const int tid = threadIdx.x;
  const int w = tid >> 6, lane = tid & 63;
  const int quad = lane >> 4, l16 = lane & 15;
  const int wx = w & 1, wy = w >> 1;  // n half / o half
  const int n0 = blockIdx.x * 64, o0 = blockIdx.y * 64, b = blockIdx.z;
  const int srow = w * 8 + (lane >> 3), scb = lane & 7;
  const unsigned short* Bbase = xt + (size_t)b * ((size_t)NSEQ * CCH);

  f32x4 acc[2][2];  // [ot][nt]
#pragma unroll
  for (int ot = 0; ot < 2; ++ot)
#pragma unroll
    for (int nt = 0; nt < 2; ++nt) acc[ot][nt] = (f32x4){0.f, 0.f, 0.f, 0.f};

  // stage c0=0 into buf 0 (64 rows each of A and B; 8 waves-worth: 4 waves x 2)
#pragma unroll
  for (int i = 0; i < 2; ++i) {
    int row = i * 32 + srow;
    int cbl = scb ^ (row & 7);
    gld16(Wp + (size_t)(o0 + row) * CCH + cbl * 8, &At[0][(i * 32 + w * 8) * 64]);
    gld16(Bbase + (size_t)(n0 + row) * CCH + cbl * 8, &Bt[0][(i * 32 + w * 8) * 64]);
  }
  __syncthreads();

  for (int it = 0; it < 16; ++it) {
    const int cur = it & 1;
    if (it < 15) {
      const int nxt = cur ^ 1;
      const int c0 = (it + 1) * 64;
#pragma unroll
      for (int i = 0; i < 2; ++i) {
        int row = i * 32 + srow;
        int cbl = scb ^ (row & 7);
        gld16(Wp + (size_t)(o0 + row) * CCH + c0 + cbl * 8, &At[nxt][(i * 32 + w * 8) * 64]);
        gld16(Bbase + (size_t)(n0 + row) * CCH + c0 + cbl * 8, &Bt[nxt][(i * 32 + w * 8) * 64]);
      }
    }
#pragma unroll
    for (int ks = 0; ks < 2; ++ks) {
      int phys = ((ks * 4 + quad) ^ (l16 & 7)) * 8;
      bf16x8 aW[2], bX[2];
#pragma unroll
      for (int ot = 0; ot < 2; ++ot)
        aW[ot] = *(const bf16x8*)&At[cur][(wy * 32 + ot * 16 + l16) * 64 + phys];
#pragma unroll
      for (int nt = 0; nt < 2; ++nt)
        bX[nt] = *(const bf16x8*)&Bt[cur][(wx * 32 + nt * 16 + l16) * 64 + phys];
#pragma unroll
      for (int ot = 0; ot < 2; ++ot)
#pragma unroll
        for (int nt = 0; nt < 2; ++nt)
          acc[ot][nt] =
              __builtin_amdgcn_mfma_f32_16x16x32_bf16(aW[ot], bX[nt], acc[ot][nt], 0, 0, 0);
    }
    __syncthreads();
  }

#pragma unroll
  for (int ot = 0; ot < 2; ++ot) {
#pragma unroll
    for (int r = 0; r < 4; ++r) {
      int o = o0 + wy * 32 + ot * 16 + quad * 4 + r;
      float br = bias[o];
#pragma unroll
      for (int nt = 0; nt < 2; ++nt)
        out[(size_t)b * ((size_t)CCH * NSEQ) + (size_t)o * NSEQ + n0 + wx * 32 + nt * 16 + l16] =
            acc[ot][nt][r] + br;
    }
  }
}

extern "C" void kernel_launch(void* const* d_in, const int* in_sizes, int n_in,
                              void* d_out, int out_size, void* d_ws, size_t ws_size,
                              hipStream_t stream) {
  const float* q = (const float*)d_in[0];
  const float* k = (const float*)d_in[1];
  const float* v = (const float*)d_in[2];
  const float* W = (const float*)d_in[3];
  const float* bias = (const float*)d_in[4];
  float* out = (float*)d_out;

  // ws layout (ushort units): Wp 1Mi | xt 4Mi | Qt 4Mi | Kt 4Mi | Vb 4Mi = 34 MiB
  unsigned short* Wp = (unsigned short*)d_ws;
  unsigned short* xt = Wp + (1u << 20);
  unsigned short* Qt = xt + (4u << 20);
  unsigned short* Kt = Qt + (4u << 20);
  unsigned short* Vb = Kt + (4u << 20);

  hipLaunchKernelGGL(prep_all, dim3(7168), dim3(256), 0, stream, W, v, q, k, Wp, Vb, Qt, Kt);
  hipLaunchKernelGGL(attn6, dim3(NSEQ / 128, H, BATCH), dim3(512), 0, stream, Qt, Kt, Vb, xt);
  hipLaunchKernelGGL(merge5, dim3(NSEQ / 64, CCH / 64, BATCH), dim3(256), 0, stream,
                     Wp, xt, bias, out);
}